// Round 16
// baseline (228.408 us; speedup 1.0000x reference)
//
#include <hip/hip_runtime.h>
#include <hip/hip_bf16.h>

typedef __attribute__((ext_vector_type(8))) short bf16x8;
typedef __attribute__((ext_vector_type(4))) float f32x4;

__device__ inline ushort f2bf(float f) {
    union { float f; unsigned u; } x; x.f = f;
    unsigned u = x.u;
    u += 0x7fffu + ((u >> 16) & 1u);   // round-to-nearest-even
    return (ushort)(u >> 16);
}

// Weights f32 (K,N) -> bf16 B-fragment layout [nt][kt][lane][8]
// mode 0: layer-1 k-permuted, K pad 608; row 580 = BIAS (A supplies 1.0 there)
__device__ __forceinline__ void pack_w(const float* __restrict__ W,
                                       const float* __restrict__ bias,
                                       ushort* __restrict__ Wp,
                                       int idx, int NKT, int Nstride, int mode) {
    int lane = idx & 63;
    int kt = (idx >> 6) % NKT;
    int nt = idx / (64 * NKT);
    int n = nt * 16 + (lane & 15);
    int kbase = kt * 32 + (lane >> 4) * 8;
    ushort o[8];
    #pragma unroll
    for (int i = 0; i < 8; ++i) {
        int k = kbase + i;
        float v = 0.0f;
        if (mode == 0) {
            if (k < 576) { int tap = k >> 6, c = k & 63; v = W[(c * 9 + tap) * Nstride + n]; }
            else if (k < 580) v = W[k * Nstride + n];
            else if (k == 580) v = bias[n];
        } else if (mode == 1) {
            v = W[k * Nstride + n];
        } else {
            v = (n == 0) ? W[k] : 0.0f;
        }
        o[i] = f2bf(v);
    }
    *reinterpret_cast<uint4*>(Wp + (size_t)idx * 8) = *reinterpret_cast<const uint4*>(o);
}

// ONE fused prep dispatch: featT transpose (blocks 0..4801) + all 5 W packs.
__global__ void prep_all_k(const float* __restrict__ feat,
                           const float* __restrict__ W0, const float* __restrict__ W1,
                           const float* __restrict__ W2, const float* __restrict__ W3,
                           const float* __restrict__ W4, const float* __restrict__ b0,
                           ushort* __restrict__ featT,
                           ushort* __restrict__ W0p, ushort* __restrict__ W1p,
                           ushort* __restrict__ W2p, ushort* __restrict__ W3p,
                           ushort* __restrict__ W4p) {
    int bid = blockIdx.x;
    if (bid < 4802) {
        // feat (B,C,H,W) f32 -> featT (B,98,98,C) bf16, zero-padded 1-px border
        int idx = bid * 256 + threadIdx.x;
        if (idx >= 2 * 98 * 98 * 64) return;
        int c = idx & 63;
        int rest = idx >> 6;
        int x = rest % 98; rest /= 98;
        int y = rest % 98;
        int b = rest / 98;
        ushort v = 0;
        if (x >= 1 && x <= 96 && y >= 1 && y <= 96)
            v = f2bf(feat[((b * 64 + c) * 96 + (y - 1)) * 96 + (x - 1)]);
        featT[idx] = v;
    } else if (bid < 4878) {
        int idx = (bid - 4802) * 256 + threadIdx.x;
        if (idx < 16 * 19 * 64) pack_w(W0, b0, W0p, idx, 19, 256, 0);
    } else if (bid < 4910) {
        int idx = (bid - 4878) * 256 + threadIdx.x;
        if (idx < 16 * 8 * 64) pack_w(W1, b0, W1p, idx, 8, 256, 1);
    } else if (bid < 4942) {
        int idx = (bid - 4910) * 256 + threadIdx.x;
        if (idx < 16 * 8 * 64) pack_w(W2, b0, W2p, idx, 8, 256, 1);
    } else if (bid < 4974) {
        int idx = (bid - 4942) * 256 + threadIdx.x;
        if (idx < 16 * 8 * 64) pack_w(W3, b0, W3p, idx, 8, 256, 1);
    } else {
        int idx = (bid - 4974) * 256 + threadIdx.x;
        if (idx < 1 * 8 * 64) pack_w(W4, b0, W4p, idx, 8, 1, 2);
    }
}

// Activations in MFMA A-fragment layout: line = rt*8+kt, position p=lane.
// Physical slot = p ^ ((p>>4)&3)  (round-9 measured: conflicts 10.9M -> 2.5M).
__device__ __forceinline__ int SW(int p) { return p ^ ((p >> 4) & 3); }

// 512 threads / 8 waves, 16 queries (64 rows).  Wave w owns col-tiles {2w,2w+1}
// = cols [32w,32w+32) = A-line w of the next layer (own-line pre-barrier MFMA).
// acc[4][2] = 32 regs; target <=85 regs -> 3 blocks/CU = 6 waves/SIMD (2x TLP).
__global__ __launch_bounds__(512, 6) void liif_main(
    const float* __restrict__ coord, const float* __restrict__ cell,
    const ushort* __restrict__ featT,
    const ushort* __restrict__ W0p, const ushort* __restrict__ W1p,
    const ushort* __restrict__ W2p, const ushort* __restrict__ W3p,
    const ushort* __restrict__ W4p,
    const float* __restrict__ b1, const float* __restrict__ b2,
    const float* __restrict__ b3, const float* __restrict__ b4,
    float* __restrict__ out)
{
    // act layout: ((rt*8 + kt)*64 + phys)*8   rt 0..3, kt 0..7   (32768 B)
    __shared__ ushort buf[4 * 8 * 64 * 8];
    __shared__ float pred_lds[64];
    __shared__ float area_lds[64];

    const int t = threadIdx.x;
    const int lane = t & 63;
    const int w = t >> 6;                   // 0..7
    const int g = lane >> 4;
    const int l15 = lane & 15;
    const int swl = SW(lane);

    // ---------------- gather setup: 8 threads per row, minimal state ----------------
    const ushort* p0;
    ushort* g_lds;
    uint ex01, ex23, ex45;
    int ps;                                  // line parity this thread gathers
    {
        const int r = t >> 3, sub8 = t & 7;  // r 0..63 row, sub8 0..7
        const int sub = sub8 & 3;            // 16B chunk within row-line
        ps = sub8 >> 2;
        const int qi = r >> 2, s = r & 3;    // row = 4*qi + shift s
        const int gq = blockIdx.x * 16 + qi; // = b*Q + q
        const int bidx = gq >> 15;           // Q = 32768
        const float vx = (s & 2) ? 1.0f : -1.0f;
        const float vy = (s & 1) ? 1.0f : -1.0f;
        const float rxf = (float)(1.0 / 96.0);
        const float lo = (float)(-1.0 + 1e-6);
        const float hi = (float)(1.0 - 1e-6);
        float c0 = coord[gq * 2 + 0], c1 = coord[gq * 2 + 1];
        float cl0 = cell[gq * 2 + 0], cl1 = cell[gq * 2 + 1];
        float sc0 = fminf(fmaxf(__fadd_rn(__fadd_rn(c0, vx * rxf), 1e-6f), lo), hi);
        float sc1 = fminf(fmaxf(__fadd_rn(__fadd_rn(c1, vy * rxf), 1e-6f), lo), hi);
        float fy = __fmul_rn(__fadd_rn(__fmul_rn(__fadd_rn(sc0, 1.0f), 96.0f), -1.0f), 0.5f);
        float fx = __fmul_rn(__fadd_rn(__fmul_rn(__fadd_rn(sc1, 1.0f), 96.0f), -1.0f), 0.5f);
        int iy = (int)rintf(fy); iy = iy < 0 ? 0 : (iy > 95 ? 95 : iy);
        int ix = (int)rintf(fx); ix = ix < 0 ? 0 : (ix > 95 ? 95 : ix);
        float qc0 = (iy + 0.5f) * (float)(2.0 / 96.0) - 1.0f;
        float qc1 = (ix + 0.5f) * (float)(2.0 / 96.0) - 1.0f;
        float rel0 = (c0 - qc0) * 96.0f;
        float rel1 = (c1 - qc1) * 96.0f;
        if (sub8 == 0) {
            area_lds[r] = fabsf(rel0 * rel1) + 1e-9f;
            asm("v_cvt_pk_bf16_f32 %0, %1, %2" : "=v"(ex01) : "v"(rel0), "v"(rel1));
            float rc0 = cl0 * 96.0f, rc1 = cl1 * 96.0f;
            asm("v_cvt_pk_bf16_f32 %0, %1, %2" : "=v"(ex23) : "v"(rc0), "v"(rc1));
            ex45 = 0x3F80u;                 // bf16(1.0) at k=580 -> bias row of W0p
        } else {
            ex01 = 0; ex23 = 0; ex45 = 0;
        }
        const int g_rt = r >> 4;
        const int g_sw = SW((r & 15) + (sub << 4));
        p0 = featT + (size_t)bidx * 98 * 98 * 64 + (iy * 98 + ix) * 64 + sub * 8;
        g_lds = buf + (g_rt * 8 * 64 + g_sw) * 8;   // + LINE*512 immediates
    }

    // act-store bases: wave w writes line w only.  value v_j of frag (rt,cc) ->
    // phys 4g + 16m + (j2^hi8), m = 2cc+hi8, j2 = j^(2cc); even j2->spE, odd->spO.
    const int hi8 = l15 >> 3;
    ushort* sp  = buf + w * 512 + g * 32 + hi8 * 128 + (l15 & 7);
    ushort* spE = sp + 8 * hi8;
    ushort* spO = sp - 8 * hi8;

    f32x4 acc[4][2];

    auto store_acts = [&]() {
        #pragma unroll
        for (int cc = 0; cc < 2; ++cc)
            #pragma unroll
            for (int rt = 0; rt < 4; ++rt) {
                float v0 = fmaxf(acc[rt][cc][0], 0.0f);
                float v1 = fmaxf(acc[rt][cc][1], 0.0f);
                float v2 = fmaxf(acc[rt][cc][2], 0.0f);
                float v3 = fmaxf(acc[rt][cc][3], 0.0f);
                uint p01, p23;
                asm("v_cvt_pk_bf16_f32 %0, %1, %2" : "=v"(p01) : "v"(v0), "v"(v1));
                asm("v_cvt_pk_bf16_f32 %0, %1, %2" : "=v"(p23) : "v"(v2), "v"(v3));
                const int off = rt * 4096 + cc * 256;
                if (cc == 0) {
                    spE[off + 0]  = (ushort)p01;
                    spO[off + 8]  = (ushort)(p01 >> 16);
                    spE[off + 16] = (ushort)p23;
                    spO[off + 24] = (ushort)(p23 >> 16);
                } else {
                    spE[off + 16] = (ushort)p01;
                    spO[off + 24] = (ushort)(p01 >> 16);
                    spE[off + 0]  = (ushort)p23;
                    spO[off + 8]  = (ushort)(p23 >> 16);
                }
            }
    };

#define LOADW0(DST, KT) do { _Pragma("unroll")                                   \
        for (int cc_ = 0; cc_ < 2; ++cc_)                                        \
            DST[cc_] = *reinterpret_cast<const bf16x8*>(                         \
                W0p + (((size_t)(w * 2 + cc_) * 19 + (KT)) * 64 + lane) * 8);    \
    } while (0)
#define LOADWX(DST, WP, KT) do { _Pragma("unroll")                               \
        for (int cc_ = 0; cc_ < 2; ++cc_)                                        \
            DST[cc_] = *reinterpret_cast<const bf16x8*>(                         \
                (WP) + (((size_t)(w * 2 + cc_) * 8 + (KT)) * 64 + lane) * 8);    \
    } while (0)
#define MFMA_LINE(BFR, LINE) do { _Pragma("unroll")                              \
        for (int rt_ = 0; rt_ < 4; ++rt_) {                                      \
            bf16x8 a_ = *reinterpret_cast<const bf16x8*>(                        \
                buf + ((rt_ * 8 + (LINE)) * 64 + swl) * 8);                      \
            _Pragma("unroll")                                                    \
            for (int cc_ = 0; cc_ < 2; ++cc_)                                    \
                acc[rt_][cc_] = __builtin_amdgcn_mfma_f32_16x16x32_bf16(         \
                    a_, BFR[cc_], acc[rt_][cc_], 0, 0, 0);                       \
        } } while (0)
// first k-line of a layer: C comes from BC[cc] (bias broadcast or zero quad)
#define MFMA_LINE_C(BFR, LINE, BC) do { _Pragma("unroll")                        \
        for (int rt_ = 0; rt_ < 4; ++rt_) {                                      \
            bf16x8 a_ = *reinterpret_cast<const bf16x8*>(                        \
                buf + ((rt_ * 8 + (LINE)) * 64 + swl) * 8);                      \
            _Pragma("unroll")                                                    \
            for (int cc_ = 0; cc_ < 2; ++cc_)                                    \
                acc[rt_][cc_] = __builtin_amdgcn_mfma_f32_16x16x32_bf16(         \
                    a_, BFR[cc_], (BC)[cc_], 0, 0, 0);                           \
        } } while (0)
#define G1(KT, LINE) do {                                                        \
        constexpr int tap_ = (KT) >> 1;                                          \
        constexpr int coff_ = ((tap_ / 3) * 98 + (tap_ % 3)) * 64 + ((KT) & 1) * 32; \
        *reinterpret_cast<uint4*>(g_lds + (LINE) * 512) =                        \
            *reinterpret_cast<const uint4*>(p0 + coff_);                         \
    } while (0)

    // ------- layer 1: 3 phases (8+8+3 k-tiles), zero-C init, bias via k=580 -------
    bf16x8 wA[2], wB[2];
    f32x4 zc[2];
    #pragma unroll
    for (int c_ = 0; c_ < 2; ++c_) { zc[c_][0] = 0.f; zc[c_][1] = 0.f; zc[c_][2] = 0.f; zc[c_][3] = 0.f; }
    if (ps == 0) { G1(0, 0); G1(2, 2); G1(4, 4); G1(6, 6); }
    else         { G1(1, 1); G1(3, 3); G1(5, 5); G1(7, 7); }
    LOADW0(wA, 0); LOADW0(wB, 1);
    __syncthreads();
    __builtin_amdgcn_s_setprio(1);
    MFMA_LINE_C(wA, 0, zc); LOADW0(wA, 2);
    MFMA_LINE(wB, 1);       LOADW0(wB, 3);
    #pragma unroll 1
    for (int i = 2; i < 8; i += 2) {
        MFMA_LINE(wA, i);     LOADW0(wA, i + 2);   // last iter preloads kt 8
        MFMA_LINE(wB, i + 1); LOADW0(wB, i + 3);   // last iter preloads kt 9
    }
    __builtin_amdgcn_s_setprio(0);
    __syncthreads();
    if (ps == 0) { G1(8, 0); G1(10, 2); G1(12, 4); G1(14, 6); }
    else         { G1(9, 1); G1(11, 3); G1(13, 5); G1(15, 7); }
    __syncthreads();
    __builtin_amdgcn_s_setprio(1);
    #pragma unroll 1
    for (int i = 0; i < 8; i += 2) {
        MFMA_LINE(wA, i);     LOADW0(wA, i + 10);  // last iter preloads kt 16
        MFMA_LINE(wB, i + 1); LOADW0(wB, i + 11);  // last iter preloads kt 17
    }
    __builtin_amdgcn_s_setprio(0);
    __syncthreads();
    if (ps == 0) {
        G1(16, 0);
        *reinterpret_cast<uint4*>(g_lds + 2 * 512) = make_uint4(ex01, ex23, ex45, 0);
    } else {
        G1(17, 1);
    }
    __syncthreads();
    __builtin_amdgcn_s_setprio(1);
    MFMA_LINE(wA, 0); LOADW0(wA, 18);
    MFMA_LINE(wB, 1);
    MFMA_LINE(wA, 2);
    __builtin_amdgcn_s_setprio(0);
    __syncthreads();

    // ------- layers 2..4: store own line w -> bias-C own-line mfma -> barrier -> rest -------
    #pragma unroll 1
    for (int layer = 0; layer < 3; ++layer) {
        const ushort* Wp = (layer == 0) ? W1p : (layer == 1) ? W2p : W3p;
        const float* bias = (layer == 0) ? b1 : (layer == 1) ? b2 : b3;
        LOADWX(wA, Wp, w);                   // L2 latency hides under store_acts
        store_acts();
        f32x4 bc[2];
        #pragma unroll
        for (int cc = 0; cc < 2; ++cc) {
            float bv = bias[(w * 2 + cc) * 16 + l15];
            bc[cc][0] = bv; bc[cc][1] = bv; bc[cc][2] = bv; bc[cc][3] = bv;
        }
        // own line w (this wave just wrote it; same-wave DS order safe)
        __builtin_amdgcn_s_setprio(1);
        LOADWX(wB, Wp, (w + 1) & 7);
        MFMA_LINE_C(wA, w, bc); LOADWX(wA, Wp, (w + 2) & 7);
        __builtin_amdgcn_s_setprio(0);
        __syncthreads();
        __builtin_amdgcn_s_setprio(1);
        MFMA_LINE(wB, (w + 1) & 7); LOADWX(wB, Wp, (w + 3) & 7);
        MFMA_LINE(wA, (w + 2) & 7); LOADWX(wA, Wp, (w + 4) & 7);
        MFMA_LINE(wB, (w + 3) & 7); LOADWX(wB, Wp, (w + 5) & 7);
        MFMA_LINE(wA, (w + 4) & 7); LOADWX(wA, Wp, (w + 6) & 7);
        MFMA_LINE(wB, (w + 5) & 7); LOADWX(wB, Wp, (w + 7) & 7);
        MFMA_LINE(wA, (w + 6) & 7);
        MFMA_LINE(wB, (w + 7) & 7);
        __builtin_amdgcn_s_setprio(0);
        __syncthreads();
    }
    // layer-4 acts
    store_acts();
    __syncthreads();

    // ---------------- layer 5: 256 -> 1 (waves 0..3 handle row-tile w) ----------------
    if (w < 4) {
        float b4v = b4[0];
        f32x4 a5;
        a5[0] = b4v; a5[1] = b4v; a5[2] = b4v; a5[3] = b4v;
        #pragma unroll
        for (int kt = 0; kt < 8; ++kt) {
            bf16x8 bb = *reinterpret_cast<const bf16x8*>(W4p + ((size_t)kt * 64 + lane) * 8);
            bf16x8 aa = *reinterpret_cast<const bf16x8*>(buf + ((w * 8 + kt) * 64 + swl) * 8);
            a5 = __builtin_amdgcn_mfma_f32_16x16x32_bf16(aa, bb, a5, 0, 0, 0);
        }
        if (l15 == 0) {
            #pragma unroll
            for (int j = 0; j < 4; ++j)
                pred_lds[w * 16 + (g << 2) + j] = a5[j];
        }
    }
    __syncthreads();

    // ---------------- local-ensemble combine (diagonal area swap) ----------------
    if (t < 16) {
        int oq = blockIdx.x * 16 + t;
        float p0v = pred_lds[t * 4 + 0], p1v = pred_lds[t * 4 + 1];
        float p2v = pred_lds[t * 4 + 2], p3v = pred_lds[t * 4 + 3];
        float a0 = area_lds[t * 4 + 0], a1 = area_lds[t * 4 + 1];
        float a2 = area_lds[t * 4 + 2], a3 = area_lds[t * 4 + 3];
        float tot = a0 + a1 + a2 + a3;
        out[oq] = (p0v * a3 + p1v * a2 + p2v * a1 + p3v * a0) / tot;
    }
#undef G1
#undef LOADW0
#undef LOADWX
#undef MFMA_LINE
#undef MFMA_LINE_C
}

extern "C" void kernel_launch(void* const* d_in, const int* in_sizes, int n_in,
                              void* d_out, int out_size, void* d_ws, size_t ws_size,
                              hipStream_t stream) {
    const float* feat  = (const float*)d_in[0];
    const float* coord = (const float*)d_in[1];
    const float* cell  = (const float*)d_in[2];
    const float* W0 = (const float*)d_in[3];
    const float* b0 = (const float*)d_in[4];
    const float* W1 = (const float*)d_in[5];
    const float* b1 = (const float*)d_in[6];
    const float* W2 = (const float*)d_in[7];
    const float* b2 = (const float*)d_in[8];
    const float* W3 = (const float*)d_in[9];
    const float* b3 = (const float*)d_in[10];
    const float* W4 = (const float*)d_in[11];
    const float* b4 = (const float*)d_in[12];
    float* out = (float*)d_out;

    ushort* featT = (ushort*)d_ws;          // 2*98*98*64      = 1229312 elems
    ushort* W0p = featT + 1229312;          // 16*19*64*8      = 155648
    ushort* W1p = W0p + 155648;             // 16*8*64*8       = 65536
    ushort* W2p = W1p + 65536;
    ushort* W3p = W2p + 65536;
    ushort* W4p = W3p + 65536;              // 1*8*64*8        = 4096

    prep_all_k<<<4976, 256, 0, stream>>>(feat, W0, W1, W2, W3, W4, b0,
                                         featT, W0p, W1p, W2p, W3p, W4p);
    liif_main<<<4096, 512, 0, stream>>>(coord, cell, featT, W0p, W1p, W2p, W3p, W4p,
                                        b1, b2, b3, b4, out);
}

// Round 17
// 183.832 us; speedup vs baseline: 1.2425x; 1.2425x over previous
//
#include <hip/hip_runtime.h>
#include <hip/hip_bf16.h>

typedef __attribute__((ext_vector_type(8))) short bf16x8;
typedef __attribute__((ext_vector_type(4))) float f32x4;

__device__ inline ushort f2bf(float f) {
    union { float f; unsigned u; } x; x.f = f;
    unsigned u = x.u;
    u += 0x7fffu + ((u >> 16) & 1u);   // round-to-nearest-even
    return (ushort)(u >> 16);
}

// Weights f32 (K,N) -> bf16 B-fragment layout [nt][kt][lane][8]
// mode 0: layer-1 k-permuted, K pad 608; row 580 = BIAS (A supplies 1.0 there)
__device__ __forceinline__ void pack_w(const float* __restrict__ W,
                                       const float* __restrict__ bias,
                                       ushort* __restrict__ Wp,
                                       int idx, int NKT, int Nstride, int mode) {
    int lane = idx & 63;
    int kt = (idx >> 6) % NKT;
    int nt = idx / (64 * NKT);
    int n = nt * 16 + (lane & 15);
    int kbase = kt * 32 + (lane >> 4) * 8;
    ushort o[8];
    #pragma unroll
    for (int i = 0; i < 8; ++i) {
        int k = kbase + i;
        float v = 0.0f;
        if (mode == 0) {
            if (k < 576) { int tap = k >> 6, c = k & 63; v = W[(c * 9 + tap) * Nstride + n]; }
            else if (k < 580) v = W[k * Nstride + n];
            else if (k == 580) v = bias[n];
        } else if (mode == 1) {
            v = W[k * Nstride + n];
        } else {
            v = (n == 0) ? W[k] : 0.0f;
        }
        o[i] = f2bf(v);
    }
    *reinterpret_cast<uint4*>(Wp + (size_t)idx * 8) = *reinterpret_cast<const uint4*>(o);
}

// ONE fused prep dispatch: featT transpose (blocks 0..4801) + all 5 W packs.
__global__ void prep_all_k(const float* __restrict__ feat,
                           const float* __restrict__ W0, const float* __restrict__ W1,
                           const float* __restrict__ W2, const float* __restrict__ W3,
                           const float* __restrict__ W4, const float* __restrict__ b0,
                           ushort* __restrict__ featT,
                           ushort* __restrict__ W0p, ushort* __restrict__ W1p,
                           ushort* __restrict__ W2p, ushort* __restrict__ W3p,
                           ushort* __restrict__ W4p) {
    int bid = blockIdx.x;
    if (bid < 4802) {
        // feat (B,C,H,W) f32 -> featT (B,98,98,C) bf16, zero-padded 1-px border
        int idx = bid * 256 + threadIdx.x;
        if (idx >= 2 * 98 * 98 * 64) return;
        int c = idx & 63;
        int rest = idx >> 6;
        int x = rest % 98; rest /= 98;
        int y = rest % 98;
        int b = rest / 98;
        ushort v = 0;
        if (x >= 1 && x <= 96 && y >= 1 && y <= 96)
            v = f2bf(feat[((b * 64 + c) * 96 + (y - 1)) * 96 + (x - 1)]);
        featT[idx] = v;
    } else if (bid < 4878) {
        int idx = (bid - 4802) * 256 + threadIdx.x;
        if (idx < 16 * 19 * 64) pack_w(W0, b0, W0p, idx, 19, 256, 0);
    } else if (bid < 4910) {
        int idx = (bid - 4878) * 256 + threadIdx.x;
        if (idx < 16 * 8 * 64) pack_w(W1, b0, W1p, idx, 8, 256, 1);
    } else if (bid < 4942) {
        int idx = (bid - 4910) * 256 + threadIdx.x;
        if (idx < 16 * 8 * 64) pack_w(W2, b0, W2p, idx, 8, 256, 1);
    } else if (bid < 4974) {
        int idx = (bid - 4942) * 256 + threadIdx.x;
        if (idx < 16 * 8 * 64) pack_w(W3, b0, W3p, idx, 8, 256, 1);
    } else {
        int idx = (bid - 4974) * 256 + threadIdx.x;
        if (idx < 1 * 8 * 64) pack_w(W4, b0, W4p, idx, 8, 1, 2);
    }
}

// Activations in MFMA A-fragment layout: line = rt*8+kt, position p=lane.
// Physical slot = p ^ ((p>>4)&3)  (round-9 measured: conflicts 10.9M -> 2.5M).
__device__ __forceinline__ int SW(int p) { return p ^ ((p >> 4) & 3); }

__global__ __launch_bounds__(256, 3) void liif_main(
    const float* __restrict__ coord, const float* __restrict__ cell,
    const ushort* __restrict__ featT,
    const ushort* __restrict__ W0p, const ushort* __restrict__ W1p,
    const ushort* __restrict__ W2p, const ushort* __restrict__ W3p,
    const ushort* __restrict__ W4p,
    const float* __restrict__ b1, const float* __restrict__ b2,
    const float* __restrict__ b3, const float* __restrict__ b4,
    float* __restrict__ out)
{
    // act layout: ((rt*8 + kt)*64 + phys)*8   rt 0..3, kt 0..7   (32768 B)
    __shared__ ushort buf[4 * 8 * 64 * 8];
    __shared__ float pred_lds[64];
    __shared__ float area_lds[64];

    const int t = threadIdx.x;
    const int lane = t & 63;
    const int w = t >> 6;
    const int g = lane >> 4;
    const int l15 = lane & 15;
    const int swl = SW(lane);

    // ---------------- gather setup: minimal persistent state ----------------
    const ushort* p0;
    ushort* g_lds;
    uint ex01, ex23, ex45;
    {
        const int r = t >> 2, sub = t & 3;          // r 0..63
        const int qi = r >> 2, s = r & 3;           // row = 4*qi + shift s
        const int gq = blockIdx.x * 16 + qi;        // = b*Q + q
        const int bidx = gq >> 15;                  // Q = 32768
        const float vx = (s & 2) ? 1.0f : -1.0f;
        const float vy = (s & 1) ? 1.0f : -1.0f;
        const float rxf = (float)(1.0 / 96.0);
        const float lo = (float)(-1.0 + 1e-6);
        const float hi = (float)(1.0 - 1e-6);
        float c0 = coord[gq * 2 + 0], c1 = coord[gq * 2 + 1];
        float cl0 = cell[gq * 2 + 0], cl1 = cell[gq * 2 + 1];
        float sc0 = fminf(fmaxf(__fadd_rn(__fadd_rn(c0, vx * rxf), 1e-6f), lo), hi);
        float sc1 = fminf(fmaxf(__fadd_rn(__fadd_rn(c1, vy * rxf), 1e-6f), lo), hi);
        float fy = __fmul_rn(__fadd_rn(__fmul_rn(__fadd_rn(sc0, 1.0f), 96.0f), -1.0f), 0.5f);
        float fx = __fmul_rn(__fadd_rn(__fmul_rn(__fadd_rn(sc1, 1.0f), 96.0f), -1.0f), 0.5f);
        int iy = (int)rintf(fy); iy = iy < 0 ? 0 : (iy > 95 ? 95 : iy);
        int ix = (int)rintf(fx); ix = ix < 0 ? 0 : (ix > 95 ? 95 : ix);
        float qc0 = (iy + 0.5f) * (float)(2.0 / 96.0) - 1.0f;
        float qc1 = (ix + 0.5f) * (float)(2.0 / 96.0) - 1.0f;
        float rel0 = (c0 - qc0) * 96.0f;
        float rel1 = (c1 - qc1) * 96.0f;
        if (sub == 0) {
            area_lds[r] = fabsf(rel0 * rel1) + 1e-9f;
            asm("v_cvt_pk_bf16_f32 %0, %1, %2" : "=v"(ex01) : "v"(rel0), "v"(rel1));
            float rc0 = cl0 * 96.0f, rc1 = cl1 * 96.0f;
            asm("v_cvt_pk_bf16_f32 %0, %1, %2" : "=v"(ex23) : "v"(rc0), "v"(rc1));
            ex45 = 0x3F80u;                 // bf16(1.0) at k=580 -> bias row of W0p
        } else {
            ex01 = 0; ex23 = 0; ex45 = 0;
        }
        const int g_rt = r >> 4;
        const int g_sw = SW((r & 15) + (sub << 4));
        p0 = featT + (size_t)bidx * 98 * 98 * 64 + (iy * 98 + ix) * 64 + sub * 8;
        g_lds = buf + (g_rt * 8 * 64 + g_sw) * 8;   // + LINE*512 immediates
    }

    // act-store bases: value v_j of frag (rt,ct) -> phys 4g + 16m + (j2^hi8),
    // m = 2(ct&1)+hi8, j2 = j^(2(ct&1)); even j2 -> spE, odd -> spO.
    const int hi8 = l15 >> 3;
    ushort* sp  = buf + w * 1024 + g * 32 + hi8 * 128 + (l15 & 7);
    ushort* spE = sp + 8 * hi8;
    ushort* spO = sp - 8 * hi8;

    f32x4 acc[4][4];

    auto store_acts = [&]() {
        #pragma unroll
        for (int ct = 0; ct < 4; ++ct)
            #pragma unroll
            for (int rt = 0; rt < 4; ++rt) {
                float v0 = fmaxf(acc[rt][ct][0], 0.0f);
                float v1 = fmaxf(acc[rt][ct][1], 0.0f);
                float v2 = fmaxf(acc[rt][ct][2], 0.0f);
                float v3 = fmaxf(acc[rt][ct][3], 0.0f);
                uint p01, p23;
                asm("v_cvt_pk_bf16_f32 %0, %1, %2" : "=v"(p01) : "v"(v0), "v"(v1));
                asm("v_cvt_pk_bf16_f32 %0, %1, %2" : "=v"(p23) : "v"(v2), "v"(v3));
                const int off = rt * 4096 + (ct >> 1) * 512 + (ct & 1) * 256;
                if ((ct & 1) == 0) {
                    spE[off + 0]  = (ushort)p01;
                    spO[off + 8]  = (ushort)(p01 >> 16);
                    spE[off + 16] = (ushort)p23;
                    spO[off + 24] = (ushort)(p23 >> 16);
                } else {
                    spE[off + 16] = (ushort)p01;
                    spO[off + 24] = (ushort)(p01 >> 16);
                    spE[off + 0]  = (ushort)p23;
                    spO[off + 8]  = (ushort)(p23 >> 16);
                }
            }
    };

#define LOADW0(DST, KT) do { _Pragma("unroll")                                   \
        for (int ct_ = 0; ct_ < 4; ++ct_)                                        \
            DST[ct_] = *reinterpret_cast<const bf16x8*>(                         \
                W0p + (((size_t)(w * 4 + ct_) * 19 + (KT)) * 64 + lane) * 8);    \
    } while (0)
#define LOADWX(DST, WP, KT) do { _Pragma("unroll")                               \
        for (int ct_ = 0; ct_ < 4; ++ct_)                                        \
            DST[ct_] = *reinterpret_cast<const bf16x8*>(                         \
                (WP) + (((size_t)(w * 4 + ct_) * 8 + (KT)) * 64 + lane) * 8);    \
    } while (0)
#define MFMA_LINE(BFR, LINE) do { _Pragma("unroll")                              \
        for (int rt_ = 0; rt_ < 4; ++rt_) {                                      \
            bf16x8 a_ = *reinterpret_cast<const bf16x8*>(                        \
                buf + ((rt_ * 8 + (LINE)) * 64 + swl) * 8);                      \
            _Pragma("unroll")                                                    \
            for (int ct_ = 0; ct_ < 4; ++ct_)                                    \
                acc[rt_][ct_] = __builtin_amdgcn_mfma_f32_16x16x32_bf16(         \
                    a_, BFR[ct_], acc[rt_][ct_], 0, 0, 0);                       \
        } } while (0)
// first k-line of a layer: C comes from BC[ct] (bias broadcast or zero quad)
#define MFMA_LINE_C(BFR, LINE, BC) do { _Pragma("unroll")                        \
        for (int rt_ = 0; rt_ < 4; ++rt_) {                                      \
            bf16x8 a_ = *reinterpret_cast<const bf16x8*>(                        \
                buf + ((rt_ * 8 + (LINE)) * 64 + swl) * 8);                      \
            _Pragma("unroll")                                                    \
            for (int ct_ = 0; ct_ < 4; ++ct_)                                    \
                acc[rt_][ct_] = __builtin_amdgcn_mfma_f32_16x16x32_bf16(         \
                    a_, BFR[ct_], (BC)[ct_], 0, 0, 0);                           \
        } } while (0)
#define G1(KT, LINE) do {                                                        \
        constexpr int tap_ = (KT) >> 1;                                          \
        constexpr int coff_ = ((tap_ / 3) * 98 + (tap_ % 3)) * 64 + ((KT) & 1) * 32; \
        *reinterpret_cast<uint4*>(g_lds + (LINE) * 512) =                        \
            *reinterpret_cast<const uint4*>(p0 + coff_);                         \
    } while (0)

    // ------- layer 1: 3 phases (8+8+3 k-tiles), 3-deep W prefetch (wA/wB/wC) -------
    bf16x8 wA[4], wB[4], wC[4];
    f32x4 zc[4];
    #pragma unroll
    for (int c_ = 0; c_ < 4; ++c_) { zc[c_][0] = 0.f; zc[c_][1] = 0.f; zc[c_][2] = 0.f; zc[c_][3] = 0.f; }
    G1(0, 0); G1(1, 1); G1(2, 2); G1(3, 3); G1(4, 4); G1(5, 5); G1(6, 6); G1(7, 7);
    LOADW0(wA, 0); LOADW0(wB, 1); LOADW0(wC, 2);
    __syncthreads();
    __builtin_amdgcn_s_setprio(1);
    MFMA_LINE_C(wA, 0, zc); LOADW0(wA, 3);
    MFMA_LINE(wB, 1);       LOADW0(wB, 4);
    MFMA_LINE(wC, 2);       LOADW0(wC, 5);
    MFMA_LINE(wA, 3);       LOADW0(wA, 6);
    MFMA_LINE(wB, 4);       LOADW0(wB, 7);
    MFMA_LINE(wC, 5);       LOADW0(wC, 8);
    MFMA_LINE(wA, 6);       LOADW0(wA, 9);
    MFMA_LINE(wB, 7);       LOADW0(wB, 10);
    __builtin_amdgcn_s_setprio(0);
    __syncthreads();
    G1(8, 0); G1(9, 1); G1(10, 2); G1(11, 3); G1(12, 4); G1(13, 5); G1(14, 6); G1(15, 7);
    __syncthreads();
    __builtin_amdgcn_s_setprio(1);
    MFMA_LINE(wC, 0);       LOADW0(wC, 11);   // line0 = kt8 (in wC)
    MFMA_LINE(wA, 1);       LOADW0(wA, 12);
    MFMA_LINE(wB, 2);       LOADW0(wB, 13);
    MFMA_LINE(wC, 3);       LOADW0(wC, 14);
    MFMA_LINE(wA, 4);       LOADW0(wA, 15);
    MFMA_LINE(wB, 5);       LOADW0(wB, 16);
    MFMA_LINE(wC, 6);       LOADW0(wC, 17);
    MFMA_LINE(wA, 7);       LOADW0(wA, 18);
    __builtin_amdgcn_s_setprio(0);
    __syncthreads();
    G1(16, 0); G1(17, 1);
    *reinterpret_cast<uint4*>(g_lds + 2 * 512) = make_uint4(ex01, ex23, ex45, 0);
    __syncthreads();
    __builtin_amdgcn_s_setprio(1);
    MFMA_LINE(wB, 0);                          // line0 = kt16 (in wB)
    MFMA_LINE(wC, 1);                          // line1 = kt17 (in wC)
    MFMA_LINE(wA, 2);                          // line2 = kt18 (in wA)
    __builtin_amdgcn_s_setprio(0);
    __syncthreads();

    // ------- layers 2..4: store -> bias-C own-kt mfma -> barrier -> rest (3-deep) -------
    #pragma unroll 1
    for (int layer = 0; layer < 3; ++layer) {
        const ushort* Wp = (layer == 0) ? W1p : (layer == 1) ? W2p : W3p;
        const float* bias = (layer == 0) ? b1 : (layer == 1) ? b2 : b3;
        const int k0 = 2 * w;
        LOADWX(wA, Wp, k0);                  // L2 latency hides under store_acts
        store_acts();
        f32x4 bc[4];
        #pragma unroll
        for (int ct = 0; ct < 4; ++ct) {
            float bv = bias[(w * 4 + ct) * 16 + l15];
            bc[ct][0] = bv; bc[ct][1] = bv; bc[ct][2] = bv; bc[ct][3] = bv;
        }
        // own col-tiles provide A for kt = 2w, 2w+1: same-wave DS order makes
        // own write->read safe; overlaps other waves' stores
        __builtin_amdgcn_s_setprio(1);
        LOADWX(wB, Wp, k0 + 1);
        LOADWX(wC, Wp, (k0 + 2) & 7);
        MFMA_LINE_C(wA, k0, bc); LOADWX(wA, Wp, (k0 + 3) & 7);
        MFMA_LINE(wB, k0 + 1);   LOADWX(wB, Wp, (k0 + 4) & 7);
        __builtin_amdgcn_s_setprio(0);
        __syncthreads();
        __builtin_amdgcn_s_setprio(1);
        MFMA_LINE(wC, (k0 + 2) & 7); LOADWX(wC, Wp, (k0 + 5) & 7);
        MFMA_LINE(wA, (k0 + 3) & 7); LOADWX(wA, Wp, (k0 + 6) & 7);
        MFMA_LINE(wB, (k0 + 4) & 7); LOADWX(wB, Wp, (k0 + 7) & 7);
        MFMA_LINE(wC, (k0 + 5) & 7);
        MFMA_LINE(wA, (k0 + 6) & 7);
        MFMA_LINE(wB, (k0 + 7) & 7);
        __builtin_amdgcn_s_setprio(0);
        __syncthreads();
    }
    // layer-4 acts
    store_acts();
    __syncthreads();

    // ---------------- layer 5: 256 -> 1 (wave w handles row-tile w) ----------------
    {
        float b4v = b4[0];
        f32x4 a5;
        a5[0] = b4v; a5[1] = b4v; a5[2] = b4v; a5[3] = b4v;
        #pragma unroll
        for (int kt = 0; kt < 8; ++kt) {
            bf16x8 bb = *reinterpret_cast<const bf16x8*>(W4p + ((size_t)kt * 64 + lane) * 8);
            bf16x8 aa = *reinterpret_cast<const bf16x8*>(buf + ((w * 8 + kt) * 64 + swl) * 8);
            a5 = __builtin_amdgcn_mfma_f32_16x16x32_bf16(aa, bb, a5, 0, 0, 0);
        }
        if (l15 == 0) {
            #pragma unroll
            for (int j = 0; j < 4; ++j)
                pred_lds[w * 16 + (g << 2) + j] = a5[j];
        }
    }
    __syncthreads();

    // ---------------- local-ensemble combine (diagonal area swap) ----------------
    if (t < 16) {
        int oq = blockIdx.x * 16 + t;
        float p0v = pred_lds[t * 4 + 0], p1v = pred_lds[t * 4 + 1];
        float p2v = pred_lds[t * 4 + 2], p3v = pred_lds[t * 4 + 3];
        float a0 = area_lds[t * 4 + 0], a1 = area_lds[t * 4 + 1];
        float a2 = area_lds[t * 4 + 2], a3 = area_lds[t * 4 + 3];
        float tot = a0 + a1 + a2 + a3;
        out[oq] = (p0v * a3 + p1v * a2 + p2v * a1 + p3v * a0) / tot;
    }
#undef G1
#undef LOADW0
#undef LOADWX
#undef MFMA_LINE
#undef MFMA_LINE_C
}

extern "C" void kernel_launch(void* const* d_in, const int* in_sizes, int n_in,
                              void* d_out, int out_size, void* d_ws, size_t ws_size,
                              hipStream_t stream) {
    const float* feat  = (const float*)d_in[0];
    const float* coord = (const float*)d_in[1];
    const float* cell  = (const float*)d_in[2];
    const float* W0 = (const float*)d_in[3];
    const float* b0 = (const float*)d_in[4];
    const float* W1 = (const float*)d_in[5];
    const float* b1 = (const float*)d_in[6];
    const float* W2 = (const float*)d_in[7];
    const float* b2 = (const float*)d_in[8];
    const float* W3 = (const float*)d_in[9];
    const float* b3 = (const float*)d_in[10];
    const float* W4 = (const float*)d_in[11];
    const float* b4 = (const float*)d_in[12];
    float* out = (float*)d_out;

    ushort* featT = (ushort*)d_ws;          // 2*98*98*64      = 1229312 elems
    ushort* W0p = featT + 1229312;          // 16*19*64*8      = 155648
    ushort* W1p = W0p + 155648;             // 16*8*64*8       = 65536
    ushort* W2p = W1p + 65536;
    ushort* W3p = W2p + 65536;
    ushort* W4p = W3p + 65536;              // 1*8*64*8        = 4096

    prep_all_k<<<4976, 256, 0, stream>>>(feat, W0, W1, W2, W3, W4, b0,
                                         featT, W0p, W1p, W2p, W3p, W4p);
    liif_main<<<4096, 256, 0, stream>>>(coord, cell, featT, W0p, W1p, W2p, W3p, W4p,
                                        b1, b2, b3, b4, out);
}

// Round 18
// 182.847 us; speedup vs baseline: 1.2492x; 1.0054x over previous
//
#include <hip/hip_runtime.h>
#include <hip/hip_bf16.h>

typedef __attribute__((ext_vector_type(8))) short bf16x8;
typedef __attribute__((ext_vector_type(4))) float f32x4;

__device__ inline ushort f2bf(float f) {
    union { float f; unsigned u; } x; x.f = f;
    unsigned u = x.u;
    u += 0x7fffu + ((u >> 16) & 1u);   // round-to-nearest-even
    return (ushort)(u >> 16);
}

// Weights f32 (K,N) -> bf16 B-fragment layout [nt][kt][lane][8]
// mode 0: layer-1 k-permuted, K pad 608; row 580 = BIAS (A supplies 1.0 there)
__device__ __forceinline__ void pack_w(const float* __restrict__ W,
                                       const float* __restrict__ bias,
                                       ushort* __restrict__ Wp,
                                       int idx, int NKT, int Nstride, int mode) {
    int lane = idx & 63;
    int kt = (idx >> 6) % NKT;
    int nt = idx / (64 * NKT);
    int n = nt * 16 + (lane & 15);
    int kbase = kt * 32 + (lane >> 4) * 8;
    ushort o[8];
    #pragma unroll
    for (int i = 0; i < 8; ++i) {
        int k = kbase + i;
        float v = 0.0f;
        if (mode == 0) {
            if (k < 576) { int tap = k >> 6, c = k & 63; v = W[(c * 9 + tap) * Nstride + n]; }
            else if (k < 580) v = W[k * Nstride + n];
            else if (k == 580) v = bias[n];
        } else if (mode == 1) {
            v = W[k * Nstride + n];
        } else {
            v = (n == 0) ? W[k] : 0.0f;
        }
        o[i] = f2bf(v);
    }
    *reinterpret_cast<uint4*>(Wp + (size_t)idx * 8) = *reinterpret_cast<const uint4*>(o);
}

// ONE fused prep dispatch: featT transpose (blocks 0..4801) + all 5 W packs.
__global__ void prep_all_k(const float* __restrict__ feat,
                           const float* __restrict__ W0, const float* __restrict__ W1,
                           const float* __restrict__ W2, const float* __restrict__ W3,
                           const float* __restrict__ W4, const float* __restrict__ b0,
                           ushort* __restrict__ featT,
                           ushort* __restrict__ W0p, ushort* __restrict__ W1p,
                           ushort* __restrict__ W2p, ushort* __restrict__ W3p,
                           ushort* __restrict__ W4p) {
    int bid = blockIdx.x;
    if (bid < 4802) {
        // feat (B,C,H,W) f32 -> featT (B,98,98,C) bf16, zero-padded 1-px border
        int idx = bid * 256 + threadIdx.x;
        if (idx >= 2 * 98 * 98 * 64) return;
        int c = idx & 63;
        int rest = idx >> 6;
        int x = rest % 98; rest /= 98;
        int y = rest % 98;
        int b = rest / 98;
        ushort v = 0;
        if (x >= 1 && x <= 96 && y >= 1 && y <= 96)
            v = f2bf(feat[((b * 64 + c) * 96 + (y - 1)) * 96 + (x - 1)]);
        featT[idx] = v;
    } else if (bid < 4878) {
        int idx = (bid - 4802) * 256 + threadIdx.x;
        if (idx < 16 * 19 * 64) pack_w(W0, b0, W0p, idx, 19, 256, 0);
    } else if (bid < 4910) {
        int idx = (bid - 4878) * 256 + threadIdx.x;
        if (idx < 16 * 8 * 64) pack_w(W1, b0, W1p, idx, 8, 256, 1);
    } else if (bid < 4942) {
        int idx = (bid - 4910) * 256 + threadIdx.x;
        if (idx < 16 * 8 * 64) pack_w(W2, b0, W2p, idx, 8, 256, 1);
    } else if (bid < 4974) {
        int idx = (bid - 4942) * 256 + threadIdx.x;
        if (idx < 16 * 8 * 64) pack_w(W3, b0, W3p, idx, 8, 256, 1);
    } else {
        int idx = (bid - 4974) * 256 + threadIdx.x;
        if (idx < 1 * 8 * 64) pack_w(W4, b0, W4p, idx, 8, 1, 2);
    }
}

// Activations in MFMA A-fragment layout: line = rt*8+kt, position p=lane.
// Physical slot = p ^ ((p>>4)&3)  (involution; round-9: conflicts 10.9M -> 2.5M).
// global_load_lds writes phys slot = lane, so lane l serves position SW(l):
// row16 = (l&15)^((l>>4)&3), chunk = l>>4.  One wave-instr per 1KB line.
__device__ __forceinline__ int SW(int p) { return p ^ ((p >> 4) & 3); }

__global__ __launch_bounds__(256, 3) void liif_main(
    const float* __restrict__ coord, const float* __restrict__ cell,
    const ushort* __restrict__ featT,
    const ushort* __restrict__ W0p, const ushort* __restrict__ W1p,
    const ushort* __restrict__ W2p, const ushort* __restrict__ W3p,
    const ushort* __restrict__ W4p,
    const float* __restrict__ b1, const float* __restrict__ b2,
    const float* __restrict__ b3, const float* __restrict__ b4,
    float* __restrict__ out)
{
    // act layout: ((rt*8 + kt)*64 + phys)*8   rt 0..3, kt 0..7   (32768 B)
    __shared__ ushort buf[4 * 8 * 64 * 8];
    __shared__ float pred_lds[64];
    __shared__ float area_lds[64];

    const int t = threadIdx.x;
    const int lane = t & 63;
    const int w = t >> 6;
    const int g = lane >> 4;
    const int l15 = lane & 15;
    const int swl = SW(lane);

    // ------- gather setup: per-lane self-contained (lane serves position SW(lane)) -------
    const ushort* p0;
    uint exA, exB, exC;
    {
        const int chunk = lane >> 4;                    // 0..3
        const int row16 = l15 ^ ((lane >> 4) & 3);      // row within wave's 16
        const int row = 16 * w + row16;                 // 0..63
        const int qi = row >> 2, s = row & 3;           // row = 4*qi + shift s
        const int gq = blockIdx.x * 16 + qi;            // = b*Q + q
        const int bidx = gq >> 15;                      // Q = 32768
        const float vx = (s & 2) ? 1.0f : -1.0f;
        const float vy = (s & 1) ? 1.0f : -1.0f;
        const float rxf = (float)(1.0 / 96.0);
        const float lo = (float)(-1.0 + 1e-6);
        const float hi = (float)(1.0 - 1e-6);
        float c0 = coord[gq * 2 + 0], c1 = coord[gq * 2 + 1];
        float cl0 = cell[gq * 2 + 0], cl1 = cell[gq * 2 + 1];
        float sc0 = fminf(fmaxf(__fadd_rn(__fadd_rn(c0, vx * rxf), 1e-6f), lo), hi);
        float sc1 = fminf(fmaxf(__fadd_rn(__fadd_rn(c1, vy * rxf), 1e-6f), lo), hi);
        float fy = __fmul_rn(__fadd_rn(__fmul_rn(__fadd_rn(sc0, 1.0f), 96.0f), -1.0f), 0.5f);
        float fx = __fmul_rn(__fadd_rn(__fmul_rn(__fadd_rn(sc1, 1.0f), 96.0f), -1.0f), 0.5f);
        int iy = (int)rintf(fy); iy = iy < 0 ? 0 : (iy > 95 ? 95 : iy);
        int ix = (int)rintf(fx); ix = ix < 0 ? 0 : (ix > 95 ? 95 : ix);
        float qc0 = (iy + 0.5f) * (float)(2.0 / 96.0) - 1.0f;
        float qc1 = (ix + 0.5f) * (float)(2.0 / 96.0) - 1.0f;
        float rel0 = (c0 - qc0) * 96.0f;
        float rel1 = (c1 - qc1) * 96.0f;
        if (chunk == 0) {
            area_lds[row] = fabsf(rel0 * rel1) + 1e-9f;
            asm("v_cvt_pk_bf16_f32 %0, %1, %2" : "=v"(exA) : "v"(rel0), "v"(rel1));
            float rc0 = cl0 * 96.0f, rc1 = cl1 * 96.0f;
            asm("v_cvt_pk_bf16_f32 %0, %1, %2" : "=v"(exB) : "v"(rc0), "v"(rc1));
            exC = 0x3F80u;                  // bf16(1.0) at k=580 -> bias row of W0p
        } else {
            exA = 0; exB = 0; exC = 0;
        }
        p0 = featT + (size_t)bidx * 98 * 98 * 64 + (iy * 98 + ix) * 64 + chunk * 8;
    }

    // act-store bases: value v_j of frag (rt,ct) -> phys 4g + 16m + (j2^hi8),
    // m = 2(ct&1)+hi8, j2 = j^(2(ct&1)); even j2 -> spE, odd -> spO.
    const int hi8 = l15 >> 3;
    ushort* sp  = buf + w * 1024 + g * 32 + hi8 * 128 + (l15 & 7);
    ushort* spE = sp + 8 * hi8;
    ushort* spO = sp - 8 * hi8;

    f32x4 acc[4][4];

    auto store_acts = [&]() {
        #pragma unroll
        for (int ct = 0; ct < 4; ++ct)
            #pragma unroll
            for (int rt = 0; rt < 4; ++rt) {
                float v0 = fmaxf(acc[rt][ct][0], 0.0f);
                float v1 = fmaxf(acc[rt][ct][1], 0.0f);
                float v2 = fmaxf(acc[rt][ct][2], 0.0f);
                float v3 = fmaxf(acc[rt][ct][3], 0.0f);
                uint p01, p23;
                asm("v_cvt_pk_bf16_f32 %0, %1, %2" : "=v"(p01) : "v"(v0), "v"(v1));
                asm("v_cvt_pk_bf16_f32 %0, %1, %2" : "=v"(p23) : "v"(v2), "v"(v3));
                const int off = rt * 4096 + (ct >> 1) * 512 + (ct & 1) * 256;
                if ((ct & 1) == 0) {
                    spE[off + 0]  = (ushort)p01;
                    spO[off + 8]  = (ushort)(p01 >> 16);
                    spE[off + 16] = (ushort)p23;
                    spO[off + 24] = (ushort)(p23 >> 16);
                } else {
                    spE[off + 16] = (ushort)p01;
                    spO[off + 24] = (ushort)(p01 >> 16);
                    spE[off + 0]  = (ushort)p23;
                    spO[off + 8]  = (ushort)(p23 >> 16);
                }
            }
    };

#define LOADW0(DST, KT) do { _Pragma("unroll")                                   \
        for (int ct_ = 0; ct_ < 4; ++ct_)                                        \
            DST[ct_] = *reinterpret_cast<const bf16x8*>(                         \
                W0p + (((size_t)(w * 4 + ct_) * 19 + (KT)) * 64 + lane) * 8);    \
    } while (0)
#define LOADWX(DST, WP, KT) do { _Pragma("unroll")                               \
        for (int ct_ = 0; ct_ < 4; ++ct_)                                        \
            DST[ct_] = *reinterpret_cast<const bf16x8*>(                         \
                (WP) + (((size_t)(w * 4 + ct_) * 8 + (KT)) * 64 + lane) * 8);    \
    } while (0)
#define MFMA_LINE(BFR, LINE) do { _Pragma("unroll")                              \
        for (int rt_ = 0; rt_ < 4; ++rt_) {                                      \
            bf16x8 a_ = *reinterpret_cast<const bf16x8*>(                        \
                buf + ((rt_ * 8 + (LINE)) * 64 + swl) * 8);                      \
            _Pragma("unroll")                                                    \
            for (int ct_ = 0; ct_ < 4; ++ct_)                                    \
                acc[rt_][ct_] = __builtin_amdgcn_mfma_f32_16x16x32_bf16(         \
                    a_, BFR[ct_], acc[rt_][ct_], 0, 0, 0);                       \
        } } while (0)
// first k-line of a layer: C comes from BC[ct] (bias broadcast or zero quad)
#define MFMA_LINE_C(BFR, LINE, BC) do { _Pragma("unroll")                        \
        for (int rt_ = 0; rt_ < 4; ++rt_) {                                      \
            bf16x8 a_ = *reinterpret_cast<const bf16x8*>(                        \
                buf + ((rt_ * 8 + (LINE)) * 64 + swl) * 8);                      \
            _Pragma("unroll")                                                    \
            for (int ct_ = 0; ct_ < 4; ++ct_)                                    \
                acc[rt_][ct_] = __builtin_amdgcn_mfma_f32_16x16x32_bf16(         \
                    a_, BFR[ct_], (BC)[ct_], 0, 0, 0);                           \
        } } while (0)
// async gather: one wave-instruction per 1KB line (lane l -> phys slot l)
#define GLDS(KT, LINE) do {                                                      \
        constexpr int tap_ = (KT) >> 1;                                          \
        constexpr int coff_ = ((tap_ / 3) * 98 + (tap_ % 3)) * 64 + ((KT) & 1) * 32; \
        __builtin_amdgcn_global_load_lds(                                        \
            (const __attribute__((address_space(1))) void*)(p0 + coff_),         \
            (__attribute__((address_space(3))) void*)(buf + (w * 8 + (LINE)) * 512), \
            16, 0, 0);                                                           \
    } while (0)

    // ------- layer 1: 5 dbuf phases of 4 kt, DMA gather overlapped with MFMA -------
    bf16x8 wA[4], wB[4];
    f32x4 zc[4];
    #pragma unroll
    for (int c_ = 0; c_ < 4; ++c_) { zc[c_][0] = 0.f; zc[c_][1] = 0.f; zc[c_][2] = 0.f; zc[c_][3] = 0.f; }
    GLDS(0, 0); GLDS(1, 1); GLDS(2, 2); GLDS(3, 3);
    LOADW0(wA, 0); LOADW0(wB, 1);
    __syncthreads();
    // phase 0: kt0-3 (lines 0-3); issue P1 (kt4-7 -> lines 4-7)
    GLDS(4, 4); GLDS(5, 5); GLDS(6, 6); GLDS(7, 7);
    __builtin_amdgcn_s_setprio(1);
    MFMA_LINE_C(wA, 0, zc); LOADW0(wA, 2);
    MFMA_LINE(wB, 1);       LOADW0(wB, 3);
    MFMA_LINE(wA, 2);       LOADW0(wA, 4);
    MFMA_LINE(wB, 3);       LOADW0(wB, 5);
    __builtin_amdgcn_s_setprio(0);
    __syncthreads();
    // phase 1: kt4-7 (lines 4-7); issue P2 (kt8-11 -> lines 0-3)
    GLDS(8, 0); GLDS(9, 1); GLDS(10, 2); GLDS(11, 3);
    __builtin_amdgcn_s_setprio(1);
    MFMA_LINE(wA, 4); LOADW0(wA, 6);
    MFMA_LINE(wB, 5); LOADW0(wB, 7);
    MFMA_LINE(wA, 6); LOADW0(wA, 8);
    MFMA_LINE(wB, 7); LOADW0(wB, 9);
    __builtin_amdgcn_s_setprio(0);
    __syncthreads();
    // phase 2: kt8-11 (lines 0-3); issue P3 (kt12-15 -> lines 4-7)
    GLDS(12, 4); GLDS(13, 5); GLDS(14, 6); GLDS(15, 7);
    __builtin_amdgcn_s_setprio(1);
    MFMA_LINE(wA, 0); LOADW0(wA, 10);
    MFMA_LINE(wB, 1); LOADW0(wB, 11);
    MFMA_LINE(wA, 2); LOADW0(wA, 12);
    MFMA_LINE(wB, 3); LOADW0(wB, 13);
    __builtin_amdgcn_s_setprio(0);
    __syncthreads();
    // phase 3: kt12-15 (lines 4-7); issue P4 (kt16,17 -> lines 0,1) + extras line 2
    GLDS(16, 0); GLDS(17, 1);
    *reinterpret_cast<uint4*>(&buf[((w * 8 + 2) * 64 + lane) * 8]) = make_uint4(exA, exB, exC, 0);
    __builtin_amdgcn_s_setprio(1);
    MFMA_LINE(wA, 4); LOADW0(wA, 14);
    MFMA_LINE(wB, 5); LOADW0(wB, 15);
    MFMA_LINE(wA, 6); LOADW0(wA, 16);
    MFMA_LINE(wB, 7); LOADW0(wB, 17);
    __builtin_amdgcn_s_setprio(0);
    __syncthreads();
    // phase 4: kt16-18 (lines 0-2)
    __builtin_amdgcn_s_setprio(1);
    MFMA_LINE(wA, 0); LOADW0(wA, 18);
    MFMA_LINE(wB, 1);
    MFMA_LINE(wA, 2);
    __builtin_amdgcn_s_setprio(0);
    __syncthreads();

    // ------- layers 2..4: store -> bias-C own-kt mfma -> barrier -> rest -------
    #pragma unroll 1
    for (int layer = 0; layer < 3; ++layer) {
        const ushort* Wp = (layer == 0) ? W1p : (layer == 1) ? W2p : W3p;
        const float* bias = (layer == 0) ? b1 : (layer == 1) ? b2 : b3;
        const int k0 = 2 * w;
        LOADWX(wA, Wp, k0);                  // L2 latency hides under store_acts
        store_acts();
        f32x4 bc[4];
        #pragma unroll
        for (int ct = 0; ct < 4; ++ct) {
            float bv = bias[(w * 4 + ct) * 16 + l15];
            bc[ct][0] = bv; bc[ct][1] = bv; bc[ct][2] = bv; bc[ct][3] = bv;
        }
        // own col-tiles provide A for kt = 2w, 2w+1: same-wave DS order makes
        // own write->read safe; overlaps other waves' stores
        __builtin_amdgcn_s_setprio(1);
        LOADWX(wB, Wp, k0 + 1);
        MFMA_LINE_C(wA, k0, bc); LOADWX(wA, Wp, (k0 + 2) & 7);
        MFMA_LINE(wB, k0 + 1);   LOADWX(wB, Wp, (k0 + 3) & 7);
        __builtin_amdgcn_s_setprio(0);
        __syncthreads();
        __builtin_amdgcn_s_setprio(1);
        MFMA_LINE(wA, (k0 + 2) & 7); LOADWX(wA, Wp, (k0 + 4) & 7);
        MFMA_LINE(wB, (k0 + 3) & 7); LOADWX(wB, Wp, (k0 + 5) & 7);
        MFMA_LINE(wA, (k0 + 4) & 7); LOADWX(wA, Wp, (k0 + 6) & 7);
        MFMA_LINE(wB, (k0 + 5) & 7); LOADWX(wB, Wp, (k0 + 7) & 7);
        MFMA_LINE(wA, (k0 + 6) & 7);
        MFMA_LINE(wB, (k0 + 7) & 7);
        __builtin_amdgcn_s_setprio(0);
        __syncthreads();
    }
    // layer-4 acts
    store_acts();
    __syncthreads();

    // ---------------- layer 5: 256 -> 1 (wave w handles row-tile w) ----------------
    {
        float b4v = b4[0];
        f32x4 a5;
        a5[0] = b4v; a5[1] = b4v; a5[2] = b4v; a5[3] = b4v;
        #pragma unroll
        for (int kt = 0; kt < 8; ++kt) {
            bf16x8 bb = *reinterpret_cast<const bf16x8*>(W4p + ((size_t)kt * 64 + lane) * 8);
            bf16x8 aa = *reinterpret_cast<const bf16x8*>(buf + ((w * 8 + kt) * 64 + swl) * 8);
            a5 = __builtin_amdgcn_mfma_f32_16x16x32_bf16(aa, bb, a5, 0, 0, 0);
        }
        if (l15 == 0) {
            #pragma unroll
            for (int j = 0; j < 4; ++j)
                pred_lds[w * 16 + (g << 2) + j] = a5[j];
        }
    }
    __syncthreads();

    // ---------------- local-ensemble combine (diagonal area swap) ----------------
    if (t < 16) {
        int oq = blockIdx.x * 16 + t;
        float p0v = pred_lds[t * 4 + 0], p1v = pred_lds[t * 4 + 1];
        float p2v = pred_lds[t * 4 + 2], p3v = pred_lds[t * 4 + 3];
        float a0 = area_lds[t * 4 + 0], a1 = area_lds[t * 4 + 1];
        float a2 = area_lds[t * 4 + 2], a3 = area_lds[t * 4 + 3];
        float tot = a0 + a1 + a2 + a3;
        out[oq] = (p0v * a3 + p1v * a2 + p2v * a1 + p3v * a0) / tot;
    }
#undef GLDS
#undef LOADW0
#undef LOADWX
#undef MFMA_LINE
#undef MFMA_LINE_C
}

extern "C" void kernel_launch(void* const* d_in, const int* in_sizes, int n_in,
                              void* d_out, int out_size, void* d_ws, size_t ws_size,
                              hipStream_t stream) {
    const float* feat  = (const float*)d_in[0];
    const float* coord = (const float*)d_in[1];
    const float* cell  = (const float*)d_in[2];
    const float* W0 = (const float*)d_in[3];
    const float* b0 = (const float*)d_in[4];
    const float* W1 = (const float*)d_in[5];
    const float* b1 = (const float*)d_in[6];
    const float* W2 = (const float*)d_in[7];
    const float* b2 = (const float*)d_in[8];
    const float* W3 = (const float*)d_in[9];
    const float* b3 = (const float*)d_in[10];
    const float* W4 = (const float*)d_in[11];
    const float* b4 = (const float*)d_in[12];
    float* out = (float*)d_out;

    ushort* featT = (ushort*)d_ws;          // 2*98*98*64      = 1229312 elems
    ushort* W0p = featT + 1229312;          // 16*19*64*8      = 155648
    ushort* W1p = W0p + 155648;             // 16*8*64*8       = 65536
    ushort* W2p = W1p + 65536;
    ushort* W3p = W2p + 65536;
    ushort* W4p = W3p + 65536;              // 1*8*64*8        = 4096

    prep_all_k<<<4976, 256, 0, stream>>>(feat, W0, W1, W2, W3, W4, b0,
                                         featT, W0p, W1p, W2p, W3p, W4p);
    liif_main<<<4096, 256, 0, stream>>>(coord, cell, featT, W0p, W1p, W2p, W3p, W4p,
                                        b1, b2, b3, b4, out);
}

// Round 19
// 182.753 us; speedup vs baseline: 1.2498x; 1.0005x over previous
//
#include <hip/hip_runtime.h>
#include <hip/hip_bf16.h>

typedef __attribute__((ext_vector_type(8))) short bf16x8;
typedef __attribute__((ext_vector_type(4))) float f32x4;

__device__ inline ushort f2bf(float f) {
    union { float f; unsigned u; } x; x.f = f;
    unsigned u = x.u;
    u += 0x7fffu + ((u >> 16) & 1u);   // round-to-nearest-even
    return (ushort)(u >> 16);
}

// Weights f32 (K,N) -> bf16 B-fragment layout [nt][kt][lane][8]
// mode 0: layer-1 k-permuted, K pad 608; row 580 = BIAS (A supplies 1.0 there)
__device__ __forceinline__ void pack_w(const float* __restrict__ W,
                                       const float* __restrict__ bias,
                                       ushort* __restrict__ Wp,
                                       int idx, int NKT, int Nstride, int mode) {
    int lane = idx & 63;
    int kt = (idx >> 6) % NKT;
    int nt = idx / (64 * NKT);
    int n = nt * 16 + (lane & 15);
    int kbase = kt * 32 + (lane >> 4) * 8;
    ushort o[8];
    #pragma unroll
    for (int i = 0; i < 8; ++i) {
        int k = kbase + i;
        float v = 0.0f;
        if (mode == 0) {
            if (k < 576) { int tap = k >> 6, c = k & 63; v = W[(c * 9 + tap) * Nstride + n]; }
            else if (k < 580) v = W[k * Nstride + n];
            else if (k == 580) v = bias[n];
        } else if (mode == 1) {
            v = W[k * Nstride + n];
        } else {
            v = (n == 0) ? W[k] : 0.0f;
        }
        o[i] = f2bf(v);
    }
    *reinterpret_cast<uint4*>(Wp + (size_t)idx * 8) = *reinterpret_cast<const uint4*>(o);
}

// ONE fused prep dispatch: featT transpose (blocks 0..4801) + all 5 W packs.
__global__ void prep_all_k(const float* __restrict__ feat,
                           const float* __restrict__ W0, const float* __restrict__ W1,
                           const float* __restrict__ W2, const float* __restrict__ W3,
                           const float* __restrict__ W4, const float* __restrict__ b0,
                           ushort* __restrict__ featT,
                           ushort* __restrict__ W0p, ushort* __restrict__ W1p,
                           ushort* __restrict__ W2p, ushort* __restrict__ W3p,
                           ushort* __restrict__ W4p) {
    int bid = blockIdx.x;
    if (bid < 4802) {
        // feat (B,C,H,W) f32 -> featT (B,98,98,C) bf16, zero-padded 1-px border
        int idx = bid * 256 + threadIdx.x;
        if (idx >= 2 * 98 * 98 * 64) return;
        int c = idx & 63;
        int rest = idx >> 6;
        int x = rest % 98; rest /= 98;
        int y = rest % 98;
        int b = rest / 98;
        ushort v = 0;
        if (x >= 1 && x <= 96 && y >= 1 && y <= 96)
            v = f2bf(feat[((b * 64 + c) * 96 + (y - 1)) * 96 + (x - 1)]);
        featT[idx] = v;
    } else if (bid < 4878) {
        int idx = (bid - 4802) * 256 + threadIdx.x;
        if (idx < 16 * 19 * 64) pack_w(W0, b0, W0p, idx, 19, 256, 0);
    } else if (bid < 4910) {
        int idx = (bid - 4878) * 256 + threadIdx.x;
        if (idx < 16 * 8 * 64) pack_w(W1, b0, W1p, idx, 8, 256, 1);
    } else if (bid < 4942) {
        int idx = (bid - 4910) * 256 + threadIdx.x;
        if (idx < 16 * 8 * 64) pack_w(W2, b0, W2p, idx, 8, 256, 1);
    } else if (bid < 4974) {
        int idx = (bid - 4942) * 256 + threadIdx.x;
        if (idx < 16 * 8 * 64) pack_w(W3, b0, W3p, idx, 8, 256, 1);
    } else {
        int idx = (bid - 4974) * 256 + threadIdx.x;
        if (idx < 1 * 8 * 64) pack_w(W4, b0, W4p, idx, 8, 1, 2);
    }
}

// Activations in MFMA A-fragment layout: line = rt*8+kt, position p=lane.
// Physical slot = p ^ ((p>>4)&3)  (involution; round-9: conflicts 10.9M -> 2.5M;
// round-18: GLDS gather -> 0).  global_load_lds writes phys slot = lane, so
// lane l serves position SW(l): row16 = (l&15)^((l>>4)&3), chunk = l>>4.
__device__ __forceinline__ int SW(int p) { return p ^ ((p >> 4) & 3); }

__global__ __launch_bounds__(256, 3) void liif_main(
    const float* __restrict__ coord, const float* __restrict__ cell,
    const ushort* __restrict__ featT,
    const ushort* __restrict__ W0p, const ushort* __restrict__ W1p,
    const ushort* __restrict__ W2p, const ushort* __restrict__ W3p,
    const ushort* __restrict__ W4p,
    const float* __restrict__ b1, const float* __restrict__ b2,
    const float* __restrict__ b3, const float* __restrict__ b4,
    float* __restrict__ out)
{
    // act layout: ((rt*8 + kt)*64 + phys)*8   rt 0..3, kt 0..7   (32768 B)
    __shared__ ushort buf[4 * 8 * 64 * 8];
    __shared__ float pred_lds[64];
    __shared__ float area_lds[64];

    const int t = threadIdx.x;
    const int lane = t & 63;
    const int w = t >> 6;
    const int g = lane >> 4;
    const int l15 = lane & 15;
    const int swl = SW(lane);

    // ------- gather setup: per-lane self-contained (lane serves position SW(lane)) -------
    const ushort* p0;
    uint exA, exB, exC;
    {
        const int chunk = lane >> 4;                    // 0..3
        const int row16 = l15 ^ ((lane >> 4) & 3);      // row within wave's 16
        const int row = 16 * w + row16;                 // 0..63
        const int qi = row >> 2, s = row & 3;           // row = 4*qi + shift s
        const int gq = blockIdx.x * 16 + qi;            // = b*Q + q
        const int bidx = gq >> 15;                      // Q = 32768
        const float vx = (s & 2) ? 1.0f : -1.0f;
        const float vy = (s & 1) ? 1.0f : -1.0f;
        const float rxf = (float)(1.0 / 96.0);
        const float lo = (float)(-1.0 + 1e-6);
        const float hi = (float)(1.0 - 1e-6);
        float c0 = coord[gq * 2 + 0], c1 = coord[gq * 2 + 1];
        float cl0 = cell[gq * 2 + 0], cl1 = cell[gq * 2 + 1];
        float sc0 = fminf(fmaxf(__fadd_rn(__fadd_rn(c0, vx * rxf), 1e-6f), lo), hi);
        float sc1 = fminf(fmaxf(__fadd_rn(__fadd_rn(c1, vy * rxf), 1e-6f), lo), hi);
        float fy = __fmul_rn(__fadd_rn(__fmul_rn(__fadd_rn(sc0, 1.0f), 96.0f), -1.0f), 0.5f);
        float fx = __fmul_rn(__fadd_rn(__fmul_rn(__fadd_rn(sc1, 1.0f), 96.0f), -1.0f), 0.5f);
        int iy = (int)rintf(fy); iy = iy < 0 ? 0 : (iy > 95 ? 95 : iy);
        int ix = (int)rintf(fx); ix = ix < 0 ? 0 : (ix > 95 ? 95 : ix);
        float qc0 = (iy + 0.5f) * (float)(2.0 / 96.0) - 1.0f;
        float qc1 = (ix + 0.5f) * (float)(2.0 / 96.0) - 1.0f;
        float rel0 = (c0 - qc0) * 96.0f;
        float rel1 = (c1 - qc1) * 96.0f;
        if (chunk == 0) {
            area_lds[row] = fabsf(rel0 * rel1) + 1e-9f;
            asm("v_cvt_pk_bf16_f32 %0, %1, %2" : "=v"(exA) : "v"(rel0), "v"(rel1));
            float rc0 = cl0 * 96.0f, rc1 = cl1 * 96.0f;
            asm("v_cvt_pk_bf16_f32 %0, %1, %2" : "=v"(exB) : "v"(rc0), "v"(rc1));
            exC = 0x3F80u;                  // bf16(1.0) at k=580 -> bias row of W0p
        } else {
            exA = 0; exB = 0; exC = 0;
        }
        p0 = featT + (size_t)bidx * 98 * 98 * 64 + (iy * 98 + ix) * 64 + chunk * 8;
    }

    // act-store bases: value v_j of frag (rt,ct) -> phys 4g + 16m + (j2^hi8),
    // m = 2(ct&1)+hi8, j2 = j^(2(ct&1)); even j2 -> spE, odd -> spO.
    const int hi8 = l15 >> 3;
    ushort* sp  = buf + w * 1024 + g * 32 + hi8 * 128 + (l15 & 7);
    ushort* spE = sp + 8 * hi8;
    ushort* spO = sp - 8 * hi8;

    f32x4 acc[4][4];

    auto store_acts = [&]() {
        #pragma unroll
        for (int ct = 0; ct < 4; ++ct)
            #pragma unroll
            for (int rt = 0; rt < 4; ++rt) {
                float v0 = fmaxf(acc[rt][ct][0], 0.0f);
                float v1 = fmaxf(acc[rt][ct][1], 0.0f);
                float v2 = fmaxf(acc[rt][ct][2], 0.0f);
                float v3 = fmaxf(acc[rt][ct][3], 0.0f);
                uint p01, p23;
                asm("v_cvt_pk_bf16_f32 %0, %1, %2" : "=v"(p01) : "v"(v0), "v"(v1));
                asm("v_cvt_pk_bf16_f32 %0, %1, %2" : "=v"(p23) : "v"(v2), "v"(v3));
                const int off = rt * 4096 + (ct >> 1) * 512 + (ct & 1) * 256;
                if ((ct & 1) == 0) {
                    spE[off + 0]  = (ushort)p01;
                    spO[off + 8]  = (ushort)(p01 >> 16);
                    spE[off + 16] = (ushort)p23;
                    spO[off + 24] = (ushort)(p23 >> 16);
                } else {
                    spE[off + 16] = (ushort)p01;
                    spO[off + 24] = (ushort)(p01 >> 16);
                    spE[off + 0]  = (ushort)p23;
                    spO[off + 8]  = (ushort)(p23 >> 16);
                }
            }
    };

#define LOADW0(DST, KT) do { _Pragma("unroll")                                   \
        for (int ct_ = 0; ct_ < 4; ++ct_)                                        \
            DST[ct_] = *reinterpret_cast<const bf16x8*>(                         \
                W0p + (((size_t)(w * 4 + ct_) * 19 + (KT)) * 64 + lane) * 8);    \
    } while (0)
#define LOADWX(DST, WP, KT) do { _Pragma("unroll")                               \
        for (int ct_ = 0; ct_ < 4; ++ct_)                                        \
            DST[ct_] = *reinterpret_cast<const bf16x8*>(                         \
                (WP) + (((size_t)(w * 4 + ct_) * 8 + (KT)) * 64 + lane) * 8);    \
    } while (0)
#define MFMA_LINE(BFR, LINE) do { _Pragma("unroll")                              \
        for (int rt_ = 0; rt_ < 4; ++rt_) {                                      \
            bf16x8 a_ = *reinterpret_cast<const bf16x8*>(                        \
                buf + ((rt_ * 8 + (LINE)) * 64 + swl) * 8);                      \
            _Pragma("unroll")                                                    \
            for (int ct_ = 0; ct_ < 4; ++ct_)                                    \
                acc[rt_][ct_] = __builtin_amdgcn_mfma_f32_16x16x32_bf16(         \
                    a_, BFR[ct_], acc[rt_][ct_], 0, 0, 0);                       \
        } } while (0)
// first k-line of a layer: C comes from BC[ct] (bias broadcast or zero quad)
#define MFMA_LINE_C(BFR, LINE, BC) do { _Pragma("unroll")                        \
        for (int rt_ = 0; rt_ < 4; ++rt_) {                                      \
            bf16x8 a_ = *reinterpret_cast<const bf16x8*>(                        \
                buf + ((rt_ * 8 + (LINE)) * 64 + swl) * 8);                      \
            _Pragma("unroll")                                                    \
            for (int ct_ = 0; ct_ < 4; ++ct_)                                    \
                acc[rt_][ct_] = __builtin_amdgcn_mfma_f32_16x16x32_bf16(         \
                    a_, BFR[ct_], (BC)[ct_], 0, 0, 0);                           \
        } } while (0)
// async gather: one wave-instruction per 1KB line (lane l -> phys slot l)
#define GLDS(KT, LINE) do {                                                      \
        constexpr int tap_ = (KT) >> 1;                                          \
        constexpr int coff_ = ((tap_ / 3) * 98 + (tap_ % 3)) * 64 + ((KT) & 1) * 32; \
        __builtin_amdgcn_global_load_lds(                                        \
            (const __attribute__((address_space(1))) void*)(p0 + coff_),         \
            (__attribute__((address_space(3))) void*)(buf + (w * 8 + (LINE)) * 512), \
            16, 0, 0);                                                           \
    } while (0)

    // ------- layer 1: R14's 3-stint structure (8+8+3), GLDS gather, W ping-pong -------
    bf16x8 wA[4], wB[4];
    f32x4 zc[4];
    #pragma unroll
    for (int c_ = 0; c_ < 4; ++c_) { zc[c_][0] = 0.f; zc[c_][1] = 0.f; zc[c_][2] = 0.f; zc[c_][3] = 0.f; }
    GLDS(0, 0); GLDS(1, 1); GLDS(2, 2); GLDS(3, 3);
    GLDS(4, 4); GLDS(5, 5); GLDS(6, 6); GLDS(7, 7);
    LOADW0(wA, 0); LOADW0(wB, 1);
    __syncthreads();
    __builtin_amdgcn_s_setprio(1);
    MFMA_LINE_C(wA, 0, zc); LOADW0(wA, 2);
    MFMA_LINE(wB, 1);       LOADW0(wB, 3);
    #pragma unroll 1
    for (int i = 2; i < 8; i += 2) {
        MFMA_LINE(wA, i);     LOADW0(wA, i + 2);   // last iter preloads kt 8
        MFMA_LINE(wB, i + 1); LOADW0(wB, i + 3);   // last iter preloads kt 9
    }
    __builtin_amdgcn_s_setprio(0);
    __syncthreads();
    GLDS(8, 0); GLDS(9, 1); GLDS(10, 2); GLDS(11, 3);
    GLDS(12, 4); GLDS(13, 5); GLDS(14, 6); GLDS(15, 7);
    __syncthreads();
    __builtin_amdgcn_s_setprio(1);
    #pragma unroll 1
    for (int i = 0; i < 8; i += 2) {
        MFMA_LINE(wA, i);     LOADW0(wA, i + 10);  // last iter preloads kt 16
        MFMA_LINE(wB, i + 1); LOADW0(wB, i + 11);  // last iter preloads kt 17
    }
    __builtin_amdgcn_s_setprio(0);
    __syncthreads();
    GLDS(16, 0); GLDS(17, 1);
    *reinterpret_cast<uint4*>(&buf[((w * 8 + 2) * 64 + lane) * 8]) = make_uint4(exA, exB, exC, 0);
    __syncthreads();
    __builtin_amdgcn_s_setprio(1);
    MFMA_LINE(wA, 0); LOADW0(wA, 18);
    MFMA_LINE(wB, 1);
    MFMA_LINE(wA, 2);
    __builtin_amdgcn_s_setprio(0);
    __syncthreads();

    // ---------------- layers 2..4: store -> bias-C own-kt mfma -> barrier -> rest ----------------
    #pragma unroll 1
    for (int layer = 0; layer < 3; ++layer) {
        const ushort* Wp = (layer == 0) ? W1p : (layer == 1) ? W2p : W3p;
        const float* bias = (layer == 0) ? b1 : (layer == 1) ? b2 : b3;
        const int k0 = 2 * w;
        LOADWX(wA, Wp, k0);                  // L2 latency hides under store_acts
        store_acts();
        f32x4 bc[4];
        #pragma unroll
        for (int ct = 0; ct < 4; ++ct) {
            float bv = bias[(w * 4 + ct) * 16 + l15];
            bc[ct][0] = bv; bc[ct][1] = bv; bc[ct][2] = bv; bc[ct][3] = bv;
        }
        // own col-tiles provide A for kt = 2w, 2w+1: same-wave DS order makes
        // own write->read safe; overlaps other waves' stores
        __builtin_amdgcn_s_setprio(1);
        LOADWX(wB, Wp, k0 + 1);
        MFMA_LINE_C(wA, k0, bc); LOADWX(wA, Wp, (k0 + 2) & 7);
        MFMA_LINE(wB, k0 + 1);   LOADWX(wB, Wp, (k0 + 3) & 7);
        __builtin_amdgcn_s_setprio(0);
        __syncthreads();
        __builtin_amdgcn_s_setprio(1);
        MFMA_LINE(wA, (k0 + 2) & 7); LOADWX(wA, Wp, (k0 + 4) & 7);
        MFMA_LINE(wB, (k0 + 3) & 7); LOADWX(wB, Wp, (k0 + 5) & 7);
        MFMA_LINE(wA, (k0 + 4) & 7); LOADWX(wA, Wp, (k0 + 6) & 7);
        MFMA_LINE(wB, (k0 + 5) & 7); LOADWX(wB, Wp, (k0 + 7) & 7);
        MFMA_LINE(wA, (k0 + 6) & 7);
        MFMA_LINE(wB, (k0 + 7) & 7);
        __builtin_amdgcn_s_setprio(0);
        __syncthreads();
    }
    // layer-4 acts
    store_acts();
    __syncthreads();

    // ---------------- layer 5: 256 -> 1 (wave w handles row-tile w) ----------------
    {
        float b4v = b4[0];
        f32x4 a5;
        a5[0] = b4v; a5[1] = b4v; a5[2] = b4v; a5[3] = b4v;
        #pragma unroll
        for (int kt = 0; kt < 8; ++kt) {
            bf16x8 bb = *reinterpret_cast<const bf16x8*>(W4p + ((size_t)kt * 64 + lane) * 8);
            bf16x8 aa = *reinterpret_cast<const bf16x8*>(buf + ((w * 8 + kt) * 64 + swl) * 8);
            a5 = __builtin_amdgcn_mfma_f32_16x16x32_bf16(aa, bb, a5, 0, 0, 0);
        }
        if (l15 == 0) {
            #pragma unroll
            for (int j = 0; j < 4; ++j)
                pred_lds[w * 16 + (g << 2) + j] = a5[j];
        }
    }
    __syncthreads();

    // ---------------- local-ensemble combine (diagonal area swap) ----------------
    if (t < 16) {
        int oq = blockIdx.x * 16 + t;
        float p0v = pred_lds[t * 4 + 0], p1v = pred_lds[t * 4 + 1];
        float p2v = pred_lds[t * 4 + 2], p3v = pred_lds[t * 4 + 3];
        float a0 = area_lds[t * 4 + 0], a1 = area_lds[t * 4 + 1];
        float a2 = area_lds[t * 4 + 2], a3 = area_lds[t * 4 + 3];
        float tot = a0 + a1 + a2 + a3;
        out[oq] = (p0v * a3 + p1v * a2 + p2v * a1 + p3v * a0) / tot;
    }
#undef GLDS
#undef LOADW0
#undef LOADWX
#undef MFMA_LINE
#undef MFMA_LINE_C
}

extern "C" void kernel_launch(void* const* d_in, const int* in_sizes, int n_in,
                              void* d_out, int out_size, void* d_ws, size_t ws_size,
                              hipStream_t stream) {
    const float* feat  = (const float*)d_in[0];
    const float* coord = (const float*)d_in[1];
    const float* cell  = (const float*)d_in[2];
    const float* W0 = (const float*)d_in[3];
    const float* b0 = (const float*)d_in[4];
    const float* W1 = (const float*)d_in[5];
    const float* b1 = (const float*)d_in[6];
    const float* W2 = (const float*)d_in[7];
    const float* b2 = (const float*)d_in[8];
    const float* W3 = (const float*)d_in[9];
    const float* b3 = (const float*)d_in[10];
    const float* W4 = (const float*)d_in[11];
    const float* b4 = (const float*)d_in[12];
    float* out = (float*)d_out;

    ushort* featT = (ushort*)d_ws;          // 2*98*98*64      = 1229312 elems
    ushort* W0p = featT + 1229312;          // 16*19*64*8      = 155648
    ushort* W1p = W0p + 155648;             // 16*8*64*8       = 65536
    ushort* W2p = W1p + 65536;
    ushort* W3p = W2p + 65536;
    ushort* W4p = W3p + 65536;              // 1*8*64*8        = 4096

    prep_all_k<<<4976, 256, 0, stream>>>(feat, W0, W1, W2, W3, W4, b0,
                                         featT, W0p, W1p, W2p, W3p, W4p);
    liif_main<<<4096, 256, 0, stream>>>(coord, cell, featT, W0p, W1p, W2p, W3p, W4p,
                                        b1, b2, b3, b4, out);
}

// Round 20
// 176.302 us; speedup vs baseline: 1.2956x; 1.0366x over previous
//
#include <hip/hip_runtime.h>
#include <hip/hip_bf16.h>

typedef __attribute__((ext_vector_type(8))) short bf16x8;
typedef __attribute__((ext_vector_type(4))) float f32x4;

__device__ inline ushort f2bf(float f) {
    union { float f; unsigned u; } x; x.f = f;
    unsigned u = x.u;
    u += 0x7fffu + ((u >> 16) & 1u);   // round-to-nearest-even
    return (ushort)(u >> 16);
}

// Weights f32 (K,N) -> bf16 B-fragment layout [nt][kt][lane][8]
// mode 0: layer-1 k-permuted, K pad 608; row 580 = BIAS (A supplies 1.0 there)
__device__ __forceinline__ void pack_w(const float* __restrict__ W,
                                       const float* __restrict__ bias,
                                       ushort* __restrict__ Wp,
                                       int idx, int NKT, int Nstride, int mode) {
    int lane = idx & 63;
    int kt = (idx >> 6) % NKT;
    int nt = idx / (64 * NKT);
    int n = nt * 16 + (lane & 15);
    int kbase = kt * 32 + (lane >> 4) * 8;
    ushort o[8];
    #pragma unroll
    for (int i = 0; i < 8; ++i) {
        int k = kbase + i;
        float v = 0.0f;
        if (mode == 0) {
            if (k < 576) { int tap = k >> 6, c = k & 63; v = W[(c * 9 + tap) * Nstride + n]; }
            else if (k < 580) v = W[k * Nstride + n];
            else if (k == 580) v = bias[n];
        } else if (mode == 1) {
            v = W[k * Nstride + n];
        } else {
            v = (n == 0) ? W[k] : 0.0f;
        }
        o[i] = f2bf(v);
    }
    *reinterpret_cast<uint4*>(Wp + (size_t)idx * 8) = *reinterpret_cast<const uint4*>(o);
}

// ONE fused prep dispatch: featT transpose (blocks 0..4801) + all 5 W packs.
__global__ void prep_all_k(const float* __restrict__ feat,
                           const float* __restrict__ W0, const float* __restrict__ W1,
                           const float* __restrict__ W2, const float* __restrict__ W3,
                           const float* __restrict__ W4, const float* __restrict__ b0,
                           ushort* __restrict__ featT,
                           ushort* __restrict__ W0p, ushort* __restrict__ W1p,
                           ushort* __restrict__ W2p, ushort* __restrict__ W3p,
                           ushort* __restrict__ W4p) {
    int bid = blockIdx.x;
    if (bid < 4802) {
        // feat (B,C,H,W) f32 -> featT (B,98,98,C) bf16, zero-padded 1-px border
        int idx = bid * 256 + threadIdx.x;
        if (idx >= 2 * 98 * 98 * 64) return;
        int c = idx & 63;
        int rest = idx >> 6;
        int x = rest % 98; rest /= 98;
        int y = rest % 98;
        int b = rest / 98;
        ushort v = 0;
        if (x >= 1 && x <= 96 && y >= 1 && y <= 96)
            v = f2bf(feat[((b * 64 + c) * 96 + (y - 1)) * 96 + (x - 1)]);
        featT[idx] = v;
    } else if (bid < 4878) {
        int idx = (bid - 4802) * 256 + threadIdx.x;
        if (idx < 16 * 19 * 64) pack_w(W0, b0, W0p, idx, 19, 256, 0);
    } else if (bid < 4910) {
        int idx = (bid - 4878) * 256 + threadIdx.x;
        if (idx < 16 * 8 * 64) pack_w(W1, b0, W1p, idx, 8, 256, 1);
    } else if (bid < 4942) {
        int idx = (bid - 4910) * 256 + threadIdx.x;
        if (idx < 16 * 8 * 64) pack_w(W2, b0, W2p, idx, 8, 256, 1);
    } else if (bid < 4974) {
        int idx = (bid - 4942) * 256 + threadIdx.x;
        if (idx < 16 * 8 * 64) pack_w(W3, b0, W3p, idx, 8, 256, 1);
    } else {
        int idx = (bid - 4974) * 256 + threadIdx.x;
        if (idx < 1 * 8 * 64) pack_w(W4, b0, W4p, idx, 8, 1, 2);
    }
}

// Activations in MFMA A-fragment layout: line = rt*8+kt, position p=lane.
// Physical slot = p ^ ((p>>4)&3)  (round-9 measured: conflicts 10.9M -> 2.5M).
__device__ __forceinline__ int SW(int p) { return p ^ ((p >> 4) & 3); }

__global__ __launch_bounds__(256, 3) void liif_main(
    const float* __restrict__ coord, const float* __restrict__ cell,
    const ushort* __restrict__ featT,
    const ushort* __restrict__ W0p, const ushort* __restrict__ W1p,
    const ushort* __restrict__ W2p, const ushort* __restrict__ W3p,
    const ushort* __restrict__ W4p,
    const float* __restrict__ b1, const float* __restrict__ b2,
    const float* __restrict__ b3, const float* __restrict__ b4,
    float* __restrict__ out)
{
    // act layout: ((rt*8 + kt)*64 + phys)*8   rt 0..3, kt 0..7   (32768 B)
    __shared__ ushort buf[4 * 8 * 64 * 8];
    __shared__ float pred_lds[64];
    __shared__ float area_lds[64];

    const int t = threadIdx.x;
    const int lane = t & 63;
    const int w = t >> 6;
    const int g = lane >> 4;
    const int l15 = lane & 15;
    const int swl = SW(lane);

    // ---------------- gather setup: minimal persistent state ----------------
    const ushort* p0;
    ushort* g_lds;
    uint ex01, ex23, ex45;
    {
        const int r = t >> 2, sub = t & 3;          // r 0..63
        const int qi = r >> 2, s = r & 3;           // row = 4*qi + shift s
        const int gq = blockIdx.x * 16 + qi;        // = b*Q + q
        const int bidx = gq >> 15;                  // Q = 32768
        const float vx = (s & 2) ? 1.0f : -1.0f;
        const float vy = (s & 1) ? 1.0f : -1.0f;
        const float rxf = (float)(1.0 / 96.0);
        const float lo = (float)(-1.0 + 1e-6);
        const float hi = (float)(1.0 - 1e-6);
        float c0 = coord[gq * 2 + 0], c1 = coord[gq * 2 + 1];
        float cl0 = cell[gq * 2 + 0], cl1 = cell[gq * 2 + 1];
        float sc0 = fminf(fmaxf(__fadd_rn(__fadd_rn(c0, vx * rxf), 1e-6f), lo), hi);
        float sc1 = fminf(fmaxf(__fadd_rn(__fadd_rn(c1, vy * rxf), 1e-6f), lo), hi);
        float fy = __fmul_rn(__fadd_rn(__fmul_rn(__fadd_rn(sc0, 1.0f), 96.0f), -1.0f), 0.5f);
        float fx = __fmul_rn(__fadd_rn(__fmul_rn(__fadd_rn(sc1, 1.0f), 96.0f), -1.0f), 0.5f);
        int iy = (int)rintf(fy); iy = iy < 0 ? 0 : (iy > 95 ? 95 : iy);
        int ix = (int)rintf(fx); ix = ix < 0 ? 0 : (ix > 95 ? 95 : ix);
        float qc0 = (iy + 0.5f) * (float)(2.0 / 96.0) - 1.0f;
        float qc1 = (ix + 0.5f) * (float)(2.0 / 96.0) - 1.0f;
        float rel0 = (c0 - qc0) * 96.0f;
        float rel1 = (c1 - qc1) * 96.0f;
        if (sub == 0) {
            area_lds[r] = fabsf(rel0 * rel1) + 1e-9f;
            asm("v_cvt_pk_bf16_f32 %0, %1, %2" : "=v"(ex01) : "v"(rel0), "v"(rel1));
            float rc0 = cl0 * 96.0f, rc1 = cl1 * 96.0f;
            asm("v_cvt_pk_bf16_f32 %0, %1, %2" : "=v"(ex23) : "v"(rc0), "v"(rc1));
            ex45 = 0x3F80u;                 // bf16(1.0) at k=580 -> bias row of W0p
        } else {
            ex01 = 0; ex23 = 0; ex45 = 0;
        }
        const int g_rt = r >> 4;
        const int g_sw = SW((r & 15) + (sub << 4));
        p0 = featT + (size_t)bidx * 98 * 98 * 64 + (iy * 98 + ix) * 64 + sub * 8;
        g_lds = buf + (g_rt * 8 * 64 + g_sw) * 8;   // + LINE*512 immediates
    }

    // act-store bases: value v_j of frag (rt,ct) -> phys 4g + 16m + (j2^hi8),
    // m = 2(ct&1)+hi8, j2 = j^(2(ct&1)); even j2 -> spE, odd -> spO.
    const int hi8 = l15 >> 3;
    ushort* sp  = buf + w * 1024 + g * 32 + hi8 * 128 + (l15 & 7);
    ushort* spE = sp + 8 * hi8;
    ushort* spO = sp - 8 * hi8;

    f32x4 acc[4][4];

    auto store_acts = [&]() {
        #pragma unroll
        for (int ct = 0; ct < 4; ++ct)
            #pragma unroll
            for (int rt = 0; rt < 4; ++rt) {
                float v0 = fmaxf(acc[rt][ct][0], 0.0f);
                float v1 = fmaxf(acc[rt][ct][1], 0.0f);
                float v2 = fmaxf(acc[rt][ct][2], 0.0f);
                float v3 = fmaxf(acc[rt][ct][3], 0.0f);
                uint p01, p23;
                asm("v_cvt_pk_bf16_f32 %0, %1, %2" : "=v"(p01) : "v"(v0), "v"(v1));
                asm("v_cvt_pk_bf16_f32 %0, %1, %2" : "=v"(p23) : "v"(v2), "v"(v3));
                const int off = rt * 4096 + (ct >> 1) * 512 + (ct & 1) * 256;
                if ((ct & 1) == 0) {
                    spE[off + 0]  = (ushort)p01;
                    spO[off + 8]  = (ushort)(p01 >> 16);
                    spE[off + 16] = (ushort)p23;
                    spO[off + 24] = (ushort)(p23 >> 16);
                } else {
                    spE[off + 16] = (ushort)p01;
                    spO[off + 24] = (ushort)(p01 >> 16);
                    spE[off + 0]  = (ushort)p23;
                    spO[off + 8]  = (ushort)(p23 >> 16);
                }
            }
    };

#define LOADW0(DST, KT) do { _Pragma("unroll")                                   \
        for (int ct_ = 0; ct_ < 4; ++ct_)                                        \
            DST[ct_] = *reinterpret_cast<const bf16x8*>(                         \
                W0p + (((size_t)(w * 4 + ct_) * 19 + (KT)) * 64 + lane) * 8);    \
    } while (0)
#define LOADWX(DST, WP, KT) do { _Pragma("unroll")                               \
        for (int ct_ = 0; ct_ < 4; ++ct_)                                        \
            DST[ct_] = *reinterpret_cast<const bf16x8*>(                         \
                (WP) + (((size_t)(w * 4 + ct_) * 8 + (KT)) * 64 + lane) * 8);    \
    } while (0)
#define MFMA_LINE(BFR, LINE) do { _Pragma("unroll")                              \
        for (int rt_ = 0; rt_ < 4; ++rt_) {                                      \
            bf16x8 a_ = *reinterpret_cast<const bf16x8*>(                        \
                buf + ((rt_ * 8 + (LINE)) * 64 + swl) * 8);                      \
            _Pragma("unroll")                                                    \
            for (int ct_ = 0; ct_ < 4; ++ct_)                                    \
                acc[rt_][ct_] = __builtin_amdgcn_mfma_f32_16x16x32_bf16(         \
                    a_, BFR[ct_], acc[rt_][ct_], 0, 0, 0);                       \
        } } while (0)
// first k-line of a layer: C comes from BC[ct] (bias broadcast or zero quad)
#define MFMA_LINE_C(BFR, LINE, BC) do { _Pragma("unroll")                        \
        for (int rt_ = 0; rt_ < 4; ++rt_) {                                      \
            bf16x8 a_ = *reinterpret_cast<const bf16x8*>(                        \
                buf + ((rt_ * 8 + (LINE)) * 64 + swl) * 8);                      \
            _Pragma("unroll")                                                    \
            for (int ct_ = 0; ct_ < 4; ++ct_)                                    \
                acc[rt_][ct_] = __builtin_amdgcn_mfma_f32_16x16x32_bf16(         \
                    a_, BFR[ct_], (BC)[ct_], 0, 0, 0);                           \
        } } while (0)
#define G1(KT, LINE) do {                                                        \
        constexpr int tap_ = (KT) >> 1;                                          \
        constexpr int coff_ = ((tap_ / 3) * 98 + (tap_ % 3)) * 64 + ((KT) & 1) * 32; \
        *reinterpret_cast<uint4*>(g_lds + (LINE) * 512) =                        \
            *reinterpret_cast<const uint4*>(p0 + coff_);                         \
    } while (0)

    // ------- layer 1: 3 phases (8+8+3 k-tiles), zero-C init, bias via k=580 -------
    bf16x8 wA[4], wB[4];
    f32x4 zc[4];
    #pragma unroll
    for (int c_ = 0; c_ < 4; ++c_) { zc[c_][0] = 0.f; zc[c_][1] = 0.f; zc[c_][2] = 0.f; zc[c_][3] = 0.f; }
    G1(0, 0); G1(1, 1); G1(2, 2); G1(3, 3); G1(4, 4); G1(5, 5); G1(6, 6); G1(7, 7);
    LOADW0(wA, 0); LOADW0(wB, 1);
    __syncthreads();
    __builtin_amdgcn_s_setprio(1);
    MFMA_LINE_C(wA, 0, zc); LOADW0(wA, 2);
    MFMA_LINE(wB, 1);       LOADW0(wB, 3);
    #pragma unroll 1
    for (int i = 2; i < 8; i += 2) {
        MFMA_LINE(wA, i);     LOADW0(wA, i + 2);   // last iter preloads kt 8 (phase 2)
        MFMA_LINE(wB, i + 1); LOADW0(wB, i + 3);   // last iter preloads kt 9
    }
    __builtin_amdgcn_s_setprio(0);
    __syncthreads();
    G1(8, 0); G1(9, 1); G1(10, 2); G1(11, 3); G1(12, 4); G1(13, 5); G1(14, 6); G1(15, 7);
    __syncthreads();
    __builtin_amdgcn_s_setprio(1);
    #pragma unroll 1
    for (int i = 0; i < 8; i += 2) {
        MFMA_LINE(wA, i);     LOADW0(wA, i + 10);  // last iter preloads kt 16 (phase 3)
        MFMA_LINE(wB, i + 1); LOADW0(wB, i + 11);  // last iter preloads kt 17
    }
    __builtin_amdgcn_s_setprio(0);
    __syncthreads();
    G1(16, 0); G1(17, 1);
    *reinterpret_cast<uint4*>(g_lds + 2 * 512) = make_uint4(ex01, ex23, ex45, 0);
    __syncthreads();
    __builtin_amdgcn_s_setprio(1);
    MFMA_LINE(wA, 0); LOADW0(wA, 18);
    MFMA_LINE(wB, 1);
    MFMA_LINE(wA, 2);
    __builtin_amdgcn_s_setprio(0);
    __syncthreads();

    // ---------------- layers 2..4: store -> bias-C own-kt mfma -> barrier -> rest ----------------
    #pragma unroll 1
    for (int layer = 0; layer < 3; ++layer) {
        store_acts();
        const ushort* Wp = (layer == 0) ? W1p : (layer == 1) ? W2p : W3p;
        const float* bias = (layer == 0) ? b1 : (layer == 1) ? b2 : b3;
        f32x4 bc[4];
        #pragma unroll
        for (int ct = 0; ct < 4; ++ct) {
            float bv = bias[(w * 4 + ct) * 16 + l15];
            bc[ct][0] = bv; bc[ct][1] = bv; bc[ct][2] = bv; bc[ct][3] = bv;
        }
        const int k0 = 2 * w;
        // own col-tiles provide A for kt = 2w, 2w+1: same-wave DS order makes
        // own write->read safe; overlaps other waves' stores
        LOADWX(wA, Wp, k0);
        __builtin_amdgcn_s_setprio(1);
        LOADWX(wB, Wp, k0 + 1);
        MFMA_LINE_C(wA, k0, bc); LOADWX(wA, Wp, (k0 + 2) & 7);
        MFMA_LINE(wB, k0 + 1);   LOADWX(wB, Wp, (k0 + 3) & 7);
        __builtin_amdgcn_s_setprio(0);
        __syncthreads();
        __builtin_amdgcn_s_setprio(1);
        MFMA_LINE(wA, (k0 + 2) & 7); LOADWX(wA, Wp, (k0 + 4) & 7);
        MFMA_LINE(wB, (k0 + 3) & 7); LOADWX(wB, Wp, (k0 + 5) & 7);
        MFMA_LINE(wA, (k0 + 4) & 7); LOADWX(wA, Wp, (k0 + 6) & 7);
        MFMA_LINE(wB, (k0 + 5) & 7); LOADWX(wB, Wp, (k0 + 7) & 7);
        MFMA_LINE(wA, (k0 + 6) & 7);
        MFMA_LINE(wB, (k0 + 7) & 7);
        __builtin_amdgcn_s_setprio(0);
        __syncthreads();
    }
    // layer-4 acts
    store_acts();
    __syncthreads();

    // ---------------- layer 5: 256 -> 1 (wave w handles row-tile w) ----------------
    {
        float b4v = b4[0];
        f32x4 a5;
        a5[0] = b4v; a5[1] = b4v; a5[2] = b4v; a5[3] = b4v;
        #pragma unroll
        for (int kt = 0; kt < 8; ++kt) {
            bf16x8 bb = *reinterpret_cast<const bf16x8*>(W4p + ((size_t)kt * 64 + lane) * 8);
            bf16x8 aa = *reinterpret_cast<const bf16x8*>(buf + ((w * 8 + kt) * 64 + swl) * 8);
            a5 = __builtin_amdgcn_mfma_f32_16x16x32_bf16(aa, bb, a5, 0, 0, 0);
        }
        if (l15 == 0) {
            #pragma unroll
            for (int j = 0; j < 4; ++j)
                pred_lds[w * 16 + (g << 2) + j] = a5[j];
        }
    }
    __syncthreads();

    // ---------------- local-ensemble combine (diagonal area swap) ----------------
    if (t < 16) {
        int oq = blockIdx.x * 16 + t;
        float p0v = pred_lds[t * 4 + 0], p1v = pred_lds[t * 4 + 1];
        float p2v = pred_lds[t * 4 + 2], p3v = pred_lds[t * 4 + 3];
        float a0 = area_lds[t * 4 + 0], a1 = area_lds[t * 4 + 1];
        float a2 = area_lds[t * 4 + 2], a3 = area_lds[t * 4 + 3];
        float tot = a0 + a1 + a2 + a3;
        out[oq] = (p0v * a3 + p1v * a2 + p2v * a1 + p3v * a0) / tot;
    }
#undef G1
#undef LOADW0
#undef LOADWX
#undef MFMA_LINE
#undef MFMA_LINE_C
}

extern "C" void kernel_launch(void* const* d_in, const int* in_sizes, int n_in,
                              void* d_out, int out_size, void* d_ws, size_t ws_size,
                              hipStream_t stream) {
    const float* feat  = (const float*)d_in[0];
    const float* coord = (const float*)d_in[1];
    const float* cell  = (const float*)d_in[2];
    const float* W0 = (const float*)d_in[3];
    const float* b0 = (const float*)d_in[4];
    const float* W1 = (const float*)d_in[5];
    const float* b1 = (const float*)d_in[6];
    const float* W2 = (const float*)d_in[7];
    const float* b2 = (const float*)d_in[8];
    const float* W3 = (const float*)d_in[9];
    const float* b3 = (const float*)d_in[10];
    const float* W4 = (const float*)d_in[11];
    const float* b4 = (const float*)d_in[12];
    float* out = (float*)d_out;

    ushort* featT = (ushort*)d_ws;          // 2*98*98*64      = 1229312 elems
    ushort* W0p = featT + 1229312;          // 16*19*64*8      = 155648
    ushort* W1p = W0p + 155648;             // 16*8*64*8       = 65536
    ushort* W2p = W1p + 65536;
    ushort* W3p = W2p + 65536;
    ushort* W4p = W3p + 65536;              // 1*8*64*8        = 4096

    prep_all_k<<<4976, 256, 0, stream>>>(feat, W0, W1, W2, W3, W4, b0,
                                         featT, W0p, W1p, W2p, W3p, W4p);
    liif_main<<<4096, 256, 0, stream>>>(coord, cell, featT, W0p, W1p, W2p, W3p, W4p,
                                        b1, b2, b3, b4, out);
}

// Round 21
// 175.747 us; speedup vs baseline: 1.2996x; 1.0032x over previous
//
#include <hip/hip_runtime.h>
#include <hip/hip_bf16.h>

typedef __attribute__((ext_vector_type(8))) short bf16x8;
typedef __attribute__((ext_vector_type(4))) float f32x4;

__device__ inline ushort f2bf(float f) {
    union { float f; unsigned u; } x; x.f = f;
    unsigned u = x.u;
    u += 0x7fffu + ((u >> 16) & 1u);   // round-to-nearest-even
    return (ushort)(u >> 16);
}

// Weights f32 (K,N) -> bf16 B-fragment layout [nt][kt][lane][8]
// mode 0: layer-1 k-permuted, K pad 608; row 580 = BIAS (A supplies 1.0 there)
__device__ __forceinline__ void pack_w(const float* __restrict__ W,
                                       const float* __restrict__ bias,
                                       ushort* __restrict__ Wp,
                                       int idx, int NKT, int Nstride, int mode) {
    int lane = idx & 63;
    int kt = (idx >> 6) % NKT;
    int nt = idx / (64 * NKT);
    int n = nt * 16 + (lane & 15);
    int kbase = kt * 32 + (lane >> 4) * 8;
    ushort o[8];
    #pragma unroll
    for (int i = 0; i < 8; ++i) {
        int k = kbase + i;
        float v = 0.0f;
        if (mode == 0) {
            if (k < 576) { int tap = k >> 6, c = k & 63; v = W[(c * 9 + tap) * Nstride + n]; }
            else if (k < 580) v = W[k * Nstride + n];
            else if (k == 580) v = bias[n];
        } else if (mode == 1) {
            v = W[k * Nstride + n];
        } else {
            v = (n == 0) ? W[k] : 0.0f;
        }
        o[i] = f2bf(v);
    }
    *reinterpret_cast<uint4*>(Wp + (size_t)idx * 8) = *reinterpret_cast<const uint4*>(o);
}

// ONE fused prep dispatch: featT transpose (blocks 0..4801) + all 5 W packs.
__global__ void prep_all_k(const float* __restrict__ feat,
                           const float* __restrict__ W0, const float* __restrict__ W1,
                           const float* __restrict__ W2, const float* __restrict__ W3,
                           const float* __restrict__ W4, const float* __restrict__ b0,
                           ushort* __restrict__ featT,
                           ushort* __restrict__ W0p, ushort* __restrict__ W1p,
                           ushort* __restrict__ W2p, ushort* __restrict__ W3p,
                           ushort* __restrict__ W4p) {
    int bid = blockIdx.x;
    if (bid < 4802) {
        // feat (B,C,H,W) f32 -> featT (B,98,98,C) bf16, zero-padded 1-px border
        int idx = bid * 256 + threadIdx.x;
        if (idx >= 2 * 98 * 98 * 64) return;
        int c = idx & 63;
        int rest = idx >> 6;
        int x = rest % 98; rest /= 98;
        int y = rest % 98;
        int b = rest / 98;
        ushort v = 0;
        if (x >= 1 && x <= 96 && y >= 1 && y <= 96)
            v = f2bf(feat[((b * 64 + c) * 96 + (y - 1)) * 96 + (x - 1)]);
        featT[idx] = v;
    } else if (bid < 4878) {
        int idx = (bid - 4802) * 256 + threadIdx.x;
        if (idx < 16 * 19 * 64) pack_w(W0, b0, W0p, idx, 19, 256, 0);
    } else if (bid < 4910) {
        int idx = (bid - 4878) * 256 + threadIdx.x;
        if (idx < 16 * 8 * 64) pack_w(W1, b0, W1p, idx, 8, 256, 1);
    } else if (bid < 4942) {
        int idx = (bid - 4910) * 256 + threadIdx.x;
        if (idx < 16 * 8 * 64) pack_w(W2, b0, W2p, idx, 8, 256, 1);
    } else if (bid < 4974) {
        int idx = (bid - 4942) * 256 + threadIdx.x;
        if (idx < 16 * 8 * 64) pack_w(W3, b0, W3p, idx, 8, 256, 1);
    } else {
        int idx = (bid - 4974) * 256 + threadIdx.x;
        if (idx < 1 * 8 * 64) pack_w(W4, b0, W4p, idx, 8, 1, 2);
    }
}

// Activations in MFMA A-fragment layout: line = rt*8+kt, position p=lane.
// Physical slot = p ^ ((p>>4)&3)  (round-9 measured: conflicts 10.9M -> 2.5M).
__device__ __forceinline__ int SW(int p) { return p ^ ((p >> 4) & 3); }

__global__ __launch_bounds__(256, 3) void liif_main(
    const float* __restrict__ coord, const float* __restrict__ cell,
    const ushort* __restrict__ featT,
    const ushort* __restrict__ W0p, const ushort* __restrict__ W1p,
    const ushort* __restrict__ W2p, const ushort* __restrict__ W3p,
    const ushort* __restrict__ W4p,
    const float* __restrict__ b1, const float* __restrict__ b2,
    const float* __restrict__ b3, const float* __restrict__ b4,
    float* __restrict__ out)
{
    // act layout (layers 2-5): ((rt*8 + kt)*64 + phys)*8   rt 0..3, kt 0..7  (first 32KB)
    // layer-1 chunk layout:    ((rt*10 + li)*64 + phys)*8  rt 0..3, li 0..9  (40KB)
    __shared__ ushort buf[4 * 10 * 64 * 8];   // 40960 B
    __shared__ float pred_lds[64];
    __shared__ float area_lds[64];

    const int t = threadIdx.x;
    const int lane = t & 63;
    const int w = t >> 6;
    const int g = lane >> 4;
    const int l15 = lane & 15;
    const int swl = SW(lane);

    // ---------------- gather setup: minimal persistent state ----------------
    const ushort* p0;
    ushort* g_lds;
    uint ex01, ex23, ex45;
    {
        const int r = t >> 2, sub = t & 3;          // r 0..63
        const int qi = r >> 2, s = r & 3;           // row = 4*qi + shift s
        const int gq = blockIdx.x * 16 + qi;        // = b*Q + q
        const int bidx = gq >> 15;                  // Q = 32768
        const float vx = (s & 2) ? 1.0f : -1.0f;
        const float vy = (s & 1) ? 1.0f : -1.0f;
        const float rxf = (float)(1.0 / 96.0);
        const float lo = (float)(-1.0 + 1e-6);
        const float hi = (float)(1.0 - 1e-6);
        float c0 = coord[gq * 2 + 0], c1 = coord[gq * 2 + 1];
        float cl0 = cell[gq * 2 + 0], cl1 = cell[gq * 2 + 1];
        float sc0 = fminf(fmaxf(__fadd_rn(__fadd_rn(c0, vx * rxf), 1e-6f), lo), hi);
        float sc1 = fminf(fmaxf(__fadd_rn(__fadd_rn(c1, vy * rxf), 1e-6f), lo), hi);
        float fy = __fmul_rn(__fadd_rn(__fmul_rn(__fadd_rn(sc0, 1.0f), 96.0f), -1.0f), 0.5f);
        float fx = __fmul_rn(__fadd_rn(__fmul_rn(__fadd_rn(sc1, 1.0f), 96.0f), -1.0f), 0.5f);
        int iy = (int)rintf(fy); iy = iy < 0 ? 0 : (iy > 95 ? 95 : iy);
        int ix = (int)rintf(fx); ix = ix < 0 ? 0 : (ix > 95 ? 95 : ix);
        float qc0 = (iy + 0.5f) * (float)(2.0 / 96.0) - 1.0f;
        float qc1 = (ix + 0.5f) * (float)(2.0 / 96.0) - 1.0f;
        float rel0 = (c0 - qc0) * 96.0f;
        float rel1 = (c1 - qc1) * 96.0f;
        if (sub == 0) {
            area_lds[r] = fabsf(rel0 * rel1) + 1e-9f;
            asm("v_cvt_pk_bf16_f32 %0, %1, %2" : "=v"(ex01) : "v"(rel0), "v"(rel1));
            float rc0 = cl0 * 96.0f, rc1 = cl1 * 96.0f;
            asm("v_cvt_pk_bf16_f32 %0, %1, %2" : "=v"(ex23) : "v"(rc0), "v"(rc1));
            ex45 = 0x3F80u;                 // bf16(1.0) at k=580 -> bias row of W0p
        } else {
            ex01 = 0; ex23 = 0; ex45 = 0;
        }
        const int g_rt = r >> 4;
        const int g_sw = SW((r & 15) + (sub << 4));
        p0 = featT + (size_t)bidx * 98 * 98 * 64 + (iy * 98 + ix) * 64 + sub * 8;
        g_lds = buf + (g_rt * 10 * 64 + g_sw) * 8;  // + LINE*512 immediates (li 0..9)
    }

    // act-store bases: value v_j of frag (rt,ct) -> phys 4g + 16m + (j2^hi8),
    // m = 2(ct&1)+hi8, j2 = j^(2(ct&1)); even j2 -> spE, odd -> spO.
    const int hi8 = l15 >> 3;
    ushort* sp  = buf + w * 1024 + g * 32 + hi8 * 128 + (l15 & 7);
    ushort* spE = sp + 8 * hi8;
    ushort* spO = sp - 8 * hi8;

    f32x4 acc[4][4];

    auto store_acts = [&]() {
        #pragma unroll
        for (int ct = 0; ct < 4; ++ct)
            #pragma unroll
            for (int rt = 0; rt < 4; ++rt) {
                float v0 = fmaxf(acc[rt][ct][0], 0.0f);
                float v1 = fmaxf(acc[rt][ct][1], 0.0f);
                float v2 = fmaxf(acc[rt][ct][2], 0.0f);
                float v3 = fmaxf(acc[rt][ct][3], 0.0f);
                uint p01, p23;
                asm("v_cvt_pk_bf16_f32 %0, %1, %2" : "=v"(p01) : "v"(v0), "v"(v1));
                asm("v_cvt_pk_bf16_f32 %0, %1, %2" : "=v"(p23) : "v"(v2), "v"(v3));
                const int off = rt * 4096 + (ct >> 1) * 512 + (ct & 1) * 256;
                if ((ct & 1) == 0) {
                    spE[off + 0]  = (ushort)p01;
                    spO[off + 8]  = (ushort)(p01 >> 16);
                    spE[off + 16] = (ushort)p23;
                    spO[off + 24] = (ushort)(p23 >> 16);
                } else {
                    spE[off + 16] = (ushort)p01;
                    spO[off + 24] = (ushort)(p01 >> 16);
                    spE[off + 0]  = (ushort)p23;
                    spO[off + 8]  = (ushort)(p23 >> 16);
                }
            }
    };

#define LOADW0(DST, KT) do { _Pragma("unroll")                                   \
        for (int ct_ = 0; ct_ < 4; ++ct_)                                        \
            DST[ct_] = *reinterpret_cast<const bf16x8*>(                         \
                W0p + (((size_t)(w * 4 + ct_) * 19 + (KT)) * 64 + lane) * 8);    \
    } while (0)
#define LOADWX(DST, WP, KT) do { _Pragma("unroll")                               \
        for (int ct_ = 0; ct_ < 4; ++ct_)                                        \
            DST[ct_] = *reinterpret_cast<const bf16x8*>(                         \
                (WP) + (((size_t)(w * 4 + ct_) * 8 + (KT)) * 64 + lane) * 8);    \
    } while (0)
// layers 2-5: act lines at stride 8
#define MFMA_LINE(BFR, LINE) do { _Pragma("unroll")                              \
        for (int rt_ = 0; rt_ < 4; ++rt_) {                                      \
            bf16x8 a_ = *reinterpret_cast<const bf16x8*>(                        \
                buf + ((rt_ * 8 + (LINE)) * 64 + swl) * 8);                      \
            _Pragma("unroll")                                                    \
            for (int ct_ = 0; ct_ < 4; ++ct_)                                    \
                acc[rt_][ct_] = __builtin_amdgcn_mfma_f32_16x16x32_bf16(         \
                    a_, BFR[ct_], acc[rt_][ct_], 0, 0, 0);                       \
        } } while (0)
#define MFMA_LINE_C(BFR, LINE, BC) do { _Pragma("unroll")                        \
        for (int rt_ = 0; rt_ < 4; ++rt_) {                                      \
            bf16x8 a_ = *reinterpret_cast<const bf16x8*>(                        \
                buf + ((rt_ * 8 + (LINE)) * 64 + swl) * 8);                      \
            _Pragma("unroll")                                                    \
            for (int ct_ = 0; ct_ < 4; ++ct_)                                    \
                acc[rt_][ct_] = __builtin_amdgcn_mfma_f32_16x16x32_bf16(         \
                    a_, BFR[ct_], (BC)[ct_], 0, 0, 0);                           \
        } } while (0)
// layer-1: chunk lines at stride 10
#define MFMA_L1(BFR, LINE) do { _Pragma("unroll")                                \
        for (int rt_ = 0; rt_ < 4; ++rt_) {                                      \
            bf16x8 a_ = *reinterpret_cast<const bf16x8*>(                        \
                buf + ((rt_ * 10 + (LINE)) * 64 + swl) * 8);                     \
            _Pragma("unroll")                                                    \
            for (int ct_ = 0; ct_ < 4; ++ct_)                                    \
                acc[rt_][ct_] = __builtin_amdgcn_mfma_f32_16x16x32_bf16(         \
                    a_, BFR[ct_], acc[rt_][ct_], 0, 0, 0);                       \
        } } while (0)
#define MFMA_L1_C(BFR, LINE, BC) do { _Pragma("unroll")                          \
        for (int rt_ = 0; rt_ < 4; ++rt_) {                                      \
            bf16x8 a_ = *reinterpret_cast<const bf16x8*>(                        \
                buf + ((rt_ * 10 + (LINE)) * 64 + swl) * 8);                     \
            _Pragma("unroll")                                                    \
            for (int ct_ = 0; ct_ < 4; ++ct_)                                    \
                acc[rt_][ct_] = __builtin_amdgcn_mfma_f32_16x16x32_bf16(         \
                    a_, BFR[ct_], (BC)[ct_], 0, 0, 0);                           \
        } } while (0)
#define G1(KT, LINE) do {                                                        \
        constexpr int tap_ = (KT) >> 1;                                          \
        constexpr int coff_ = ((tap_ / 3) * 98 + (tap_ % 3)) * 64 + ((KT) & 1) * 32; \
        *reinterpret_cast<uint4*>(g_lds + (LINE) * 512) =                        \
            *reinterpret_cast<const uint4*>(p0 + coff_);                         \
    } while (0)

    // ------- layer 1: 2 stints (10 + 9 k-tiles), 40KB chunk buffer, W ping-pong -------
    bf16x8 wA[4], wB[4];
    f32x4 zc[4];
    #pragma unroll
    for (int c_ = 0; c_ < 4; ++c_) { zc[c_][0] = 0.f; zc[c_][1] = 0.f; zc[c_][2] = 0.f; zc[c_][3] = 0.f; }
    G1(0, 0); G1(1, 1); G1(2, 2); G1(3, 3); G1(4, 4);
    G1(5, 5); G1(6, 6); G1(7, 7); G1(8, 8); G1(9, 9);
    LOADW0(wA, 0); LOADW0(wB, 1);
    __syncthreads();
    __builtin_amdgcn_s_setprio(1);
    MFMA_L1_C(wA, 0, zc); LOADW0(wA, 2);
    MFMA_L1(wB, 1);       LOADW0(wB, 3);
    #pragma unroll 1
    for (int i = 2; i < 10; i += 2) {
        MFMA_L1(wA, i);     LOADW0(wA, i + 2);   // last iter preloads kt 10
        MFMA_L1(wB, i + 1); LOADW0(wB, i + 3);   // last iter preloads kt 11
    }
    __builtin_amdgcn_s_setprio(0);
    __syncthreads();
    G1(10, 0); G1(11, 1); G1(12, 2); G1(13, 3);
    G1(14, 4); G1(15, 5); G1(16, 6); G1(17, 7);
    *reinterpret_cast<uint4*>(g_lds + 8 * 512) = make_uint4(ex01, ex23, ex45, 0);  // kt18 -> li8
    __syncthreads();
    __builtin_amdgcn_s_setprio(1);
    #pragma unroll 1
    for (int i = 0; i < 6; i += 2) {
        MFMA_L1(wA, i);     LOADW0(wA, i + 12);  // li i   = kt 10+i
        MFMA_L1(wB, i + 1); LOADW0(wB, i + 13);
    }
    MFMA_L1(wA, 6); LOADW0(wA, 18);              // kt16; preload kt18
    MFMA_L1(wB, 7);                              // kt17
    MFMA_L1(wA, 8);                              // kt18 (extras + bias row)
    __builtin_amdgcn_s_setprio(0);
    __syncthreads();

    // ---------------- layers 2..4: store -> bias-C own-kt mfma -> barrier -> rest ----------------
    #pragma unroll 1
    for (int layer = 0; layer < 3; ++layer) {
        store_acts();
        const ushort* Wp = (layer == 0) ? W1p : (layer == 1) ? W2p : W3p;
        const float* bias = (layer == 0) ? b1 : (layer == 1) ? b2 : b3;
        f32x4 bc[4];
        #pragma unroll
        for (int ct = 0; ct < 4; ++ct) {
            float bv = bias[(w * 4 + ct) * 16 + l15];
            bc[ct][0] = bv; bc[ct][1] = bv; bc[ct][2] = bv; bc[ct][3] = bv;
        }
        const int k0 = 2 * w;
        // own col-tiles provide A for kt = 2w, 2w+1: same-wave DS order makes
        // own write->read safe; overlaps other waves' stores
        LOADWX(wA, Wp, k0);
        __builtin_amdgcn_s_setprio(1);
        LOADWX(wB, Wp, k0 + 1);
        MFMA_LINE_C(wA, k0, bc); LOADWX(wA, Wp, (k0 + 2) & 7);
        MFMA_LINE(wB, k0 + 1);   LOADWX(wB, Wp, (k0 + 3) & 7);
        __builtin_amdgcn_s_setprio(0);
        __syncthreads();
        __builtin_amdgcn_s_setprio(1);
        MFMA_LINE(wA, (k0 + 2) & 7); LOADWX(wA, Wp, (k0 + 4) & 7);
        MFMA_LINE(wB, (k0 + 3) & 7); LOADWX(wB, Wp, (k0 + 5) & 7);
        MFMA_LINE(wA, (k0 + 4) & 7); LOADWX(wA, Wp, (k0 + 6) & 7);
        MFMA_LINE(wB, (k0 + 5) & 7); LOADWX(wB, Wp, (k0 + 7) & 7);
        MFMA_LINE(wA, (k0 + 6) & 7);
        MFMA_LINE(wB, (k0 + 7) & 7);
        __builtin_amdgcn_s_setprio(0);
        __syncthreads();
    }
    // layer-4 acts
    store_acts();
    __syncthreads();

    // ---------------- layer 5: 256 -> 1 (wave w handles row-tile w) ----------------
    {
        float b4v = b4[0];
        f32x4 a5;
        a5[0] = b4v; a5[1] = b4v; a5[2] = b4v; a5[3] = b4v;
        #pragma unroll
        for (int kt = 0; kt < 8; ++kt) {
            bf16x8 bb = *reinterpret_cast<const bf16x8*>(W4p + ((size_t)kt * 64 + lane) * 8);
            bf16x8 aa = *reinterpret_cast<const bf16x8*>(buf + ((w * 8 + kt) * 64 + swl) * 8);
            a5 = __builtin_amdgcn_mfma_f32_16x16x32_bf16(aa, bb, a5, 0, 0, 0);
        }
        if (l15 == 0) {
            #pragma unroll
            for (int j = 0; j < 4; ++j)
                pred_lds[w * 16 + (g << 2) + j] = a5[j];
        }
    }
    __syncthreads();

    // ---------------- local-ensemble combine (diagonal area swap) ----------------
    if (t < 16) {
        int oq = blockIdx.x * 16 + t;
        float p0v = pred_lds[t * 4 + 0], p1v = pred_lds[t * 4 + 1];
        float p2v = pred_lds[t * 4 + 2], p3v = pred_lds[t * 4 + 3];
        float a0 = area_lds[t * 4 + 0], a1 = area_lds[t * 4 + 1];
        float a2 = area_lds[t * 4 + 2], a3 = area_lds[t * 4 + 3];
        float tot = a0 + a1 + a2 + a3;
        out[oq] = (p0v * a3 + p1v * a2 + p2v * a1 + p3v * a0) / tot;
    }
#undef G1
#undef LOADW0
#undef LOADWX
#undef MFMA_LINE
#undef MFMA_LINE_C
#undef MFMA_L1
#undef MFMA_L1_C
}

extern "C" void kernel_launch(void* const* d_in, const int* in_sizes, int n_in,
                              void* d_out, int out_size, void* d_ws, size_t ws_size,
                              hipStream_t stream) {
    const float* feat  = (const float*)d_in[0];
    const float* coord = (const float*)d_in[1];
    const float* cell  = (const float*)d_in[2];
    const float* W0 = (const float*)d_in[3];
    const float* b0 = (const float*)d_in[4];
    const float* W1 = (const float*)d_in[5];
    const float* b1 = (const float*)d_in[6];
    const float* W2 = (const float*)d_in[7];
    const float* b2 = (const float*)d_in[8];
    const float* W3 = (const float*)d_in[9];
    const float* b3 = (const float*)d_in[10];
    const float* W4 = (const float*)d_in[11];
    const float* b4 = (const float*)d_in[12];
    float* out = (float*)d_out;

    ushort* featT = (ushort*)d_ws;          // 2*98*98*64      = 1229312 elems
    ushort* W0p = featT + 1229312;          // 16*19*64*8      = 155648
    ushort* W1p = W0p + 155648;             // 16*8*64*8       = 65536
    ushort* W2p = W1p + 65536;
    ushort* W3p = W2p + 65536;
    ushort* W4p = W3p + 65536;              // 1*8*64*8        = 4096

    prep_all_k<<<4976, 256, 0, stream>>>(feat, W0, W1, W2, W3, W4, b0,
                                         featT, W0p, W1p, W2p, W3p, W4p);
    liif_main<<<4096, 256, 0, stream>>>(coord, cell, featT, W0p, W1p, W2p, W3p, W4p,
                                        b1, b2, b3, b4, out);
}